// Round 2
// baseline (2756.637 us; speedup 1.0000x reference)
//
#include <hip/hip_runtime.h>
#include <hip/hip_bf16.h>

#define NN 50000      // nodes
#define NE 1600000    // edges
#define NG 128        // graphs
#define NB 128        // rna batch
#define SG 3000       // global seq (channels)
#define SL 2998       // local seq
#define VG 5          // global vocab
#define VL 65         // local vocab

// ---------------- graph prep ----------------
__global__ void k_edge_deg(const int* __restrict__ dst, const float* __restrict__ ew,
                           int* cnt, float* degw){
    int e = blockIdx.x*256 + threadIdx.x;
    if (e >= NE) return;
    int d = dst[e];
    atomicAdd(&cnt[d], 1);
    atomicAdd(&degw[d], ew[e]);
}

__global__ void k_node_dis(const int* __restrict__ cnt, const float* __restrict__ degw,
                           float* dis1, float* dis2, float* self1, float* self2){
    int i = blockIdx.x*256 + threadIdx.x;
    if (i >= NN) return;
    float d1 = degw[i] + 1.0f;
    float r1 = rsqrtf(d1);
    dis1[i] = r1; self1[i] = r1*r1;
    float d2 = (float)cnt[i] + 1.0f;
    float r2 = rsqrtf(d2);
    dis2[i] = r2; self2[i] = r2*r2;
}

__global__ void k_scan1(const int* __restrict__ cnt, int* bsum){
    __shared__ int sd[256];
    int t = threadIdx.x;
    int base = blockIdx.x*1024;
    int s = 0;
    #pragma unroll
    for (int j = 0; j < 4; ++j){
        int idx = base + t*4 + j;
        if (idx < NN) s += cnt[idx];
    }
    sd[t] = s; __syncthreads();
    for (int d = 128; d > 0; d >>= 1){
        if (t < d) sd[t] += sd[t+d];
        __syncthreads();
    }
    if (t == 0) bsum[blockIdx.x] = sd[0];
}

__global__ void k_scan2(int* bsum, int nb){
    if (threadIdx.x == 0 && blockIdx.x == 0){
        int run = 0;
        for (int i = 0; i < nb; ++i){ int v = bsum[i]; bsum[i] = run; run += v; }
    }
}

__global__ void k_scan3(const int* __restrict__ cnt, const int* __restrict__ bsum,
                        int* __restrict__ offs){
    __shared__ int sd[256];
    int t = threadIdx.x;
    int base = blockIdx.x*1024;
    int loc[4]; int s = 0;
    #pragma unroll
    for (int j = 0; j < 4; ++j){
        int idx = base + t*4 + j;
        loc[j] = (idx < NN) ? cnt[idx] : 0;
        s += loc[j];
    }
    sd[t] = s; __syncthreads();
    for (int d = 1; d < 256; d <<= 1){
        int v = (t >= d) ? sd[t-d] : 0;
        __syncthreads();
        sd[t] += v;
        __syncthreads();
    }
    int run = bsum[blockIdx.x] + (sd[t] - s);   // exclusive within block
    #pragma unroll
    for (int j = 0; j < 4; ++j){
        int idx = base + t*4 + j;
        if (idx < NN) offs[idx] = run;
        run += loc[j];
    }
}

__global__ void k_edge_scatter(const int* __restrict__ src, const int* __restrict__ dst,
                               const float* __restrict__ ew,
                               const float* __restrict__ dis1, const float* __restrict__ dis2,
                               const int* __restrict__ offs, int* cursor,
                               int* __restrict__ esrc, float* __restrict__ en1,
                               float* __restrict__ en2){
    int e = blockIdx.x*256 + threadIdx.x;
    if (e >= NE) return;
    int s = src[e], d = dst[e];
    int p = offs[d] + atomicAdd(&cursor[d], 1);
    esrc[p] = s;
    en1[p] = dis1[s] * ew[e] * dis1[d];
    en2[p] = dis2[s] * dis2[d];
}

// agg[i,f] = selfw[i]*x[i,f] + sum_e norm[e]*x[src_e,f]   (aggregate BEFORE W)
__global__ void k_agg(const float* __restrict__ x, const int* __restrict__ esrc,
                      const float* __restrict__ en, const int* __restrict__ offs,
                      const int* __restrict__ cnt, const float* __restrict__ selfw,
                      float* __restrict__ agg, int F){
    int i = blockIdx.x;
    int f = threadIdx.x;
    if (f >= F) return;
    float acc = selfw[i] * x[i*F + f];
    int b = offs[i];
    int e = b + cnt[i];
    int p = b;
    for (; p + 4 <= e; p += 4){
        int s0 = esrc[p], s1 = esrc[p+1], s2 = esrc[p+2], s3 = esrc[p+3];
        float n0 = en[p], n1 = en[p+1], n2 = en[p+2], n3 = en[p+3];
        float v0 = x[s0*F + f];
        float v1 = x[s1*F + f];
        float v2 = x[s2*F + f];
        float v3 = x[s3*F + f];
        acc += n0*v0; acc += n1*v1; acc += n2*v2; acc += n3*v3;
    }
    for (; p < e; ++p) acc += en[p] * x[esrc[p]*F + f];
    agg[i*F + f] = acc;
}

// t[i,j] = sum_f agg[i,f] * W[f,j] + b[j]
__global__ void k_gemm_node(const float* __restrict__ x, const float* __restrict__ W,
                            const float* __restrict__ bias, float* __restrict__ out,
                            int F, int OF){
    int i = blockIdx.x, j = threadIdx.x;
    if (j >= OF) return;
    float acc = bias[j];
    const float* xr = x + i*F;
    #pragma unroll 4
    for (int f = 0; f < F; ++f) acc += xr[f] * W[f*OF + j];
    out[i*OF + j] = acc;
}

__global__ void k_bn_stats(const float* __restrict__ t, float* __restrict__ sums, int OF){
    int f = threadIdx.x;
    if (f >= OF) return;
    float s = 0.f, ss = 0.f;
    for (int i = blockIdx.x; i < NN; i += gridDim.x){
        float v = t[i*OF + f];
        s += v; ss += v*v;
    }
    atomicAdd(&sums[f], s);
    atomicAdd(&sums[OF + f], ss);
}

__global__ void k_bn_finalize(const float* __restrict__ sums, const float* __restrict__ g,
                              const float* __restrict__ b, float* scale, float* shift, int OF){
    int f = threadIdx.x;
    if (f >= OF) return;
    float m = sums[f] / (float)NN;
    float v = sums[OF + f] / (float)NN - m*m;
    float sc = g[f] * rsqrtf(v + 1e-5f);
    scale[f] = sc;
    shift[f] = b[f] - m*sc;
}

__global__ void k_bn_apply(const float* __restrict__ t, const float* __restrict__ scale,
                           const float* __restrict__ shift, float* __restrict__ xo, int OF){
    int i = blockIdx.x, f = threadIdx.x;
    if (f >= OF) return;
    float v = t[i*OF + f] * scale[f] + shift[f];
    xo[i*OF + f] = v > 0.f ? v : 0.f;
}

__global__ void k_pool_cnt(const int* __restrict__ batch, float* cntg){
    int i = blockIdx.x*256 + threadIdx.x;
    if (i >= NN) return;
    atomicAdd(&cntg[batch[i]], 1.0f);
}

__global__ void k_pool_sum(const float* __restrict__ x, const int* __restrict__ batch,
                           float* poolsum){
    int id = blockIdx.x*256 + threadIdx.x;
    if (id >= NN*132) return;
    int i = id / 132, f = id - i*132;
    atomicAdd(&poolsum[batch[i]*132 + f], x[id]);
}

__global__ void k_fcg1(const float* __restrict__ poolsum, const float* __restrict__ cntg,
                       const float* __restrict__ W, const float* __restrict__ bias,
                       float* __restrict__ h){
    __shared__ float pr[132];
    int g = blockIdx.x, t = threadIdx.x;
    float inv = 1.0f / fmaxf(cntg[g], 1.0f);
    if (t < 132) pr[t] = poolsum[g*132 + t] * inv;
    __syncthreads();
    for (int j = t; j < 1024; j += blockDim.x){
        float acc = bias[j];
        #pragma unroll 4
        for (int f = 0; f < 132; ++f) acc += pr[f] * W[f*1024 + j];
        h[g*1024 + j] = acc > 0.f ? acc : 0.f;
    }
}

__global__ void k_fcg2(const float* __restrict__ h, const float* __restrict__ W,
                       const float* __restrict__ bias, float* __restrict__ out){
    __shared__ float hr[1024];
    int g = blockIdx.x, t = threadIdx.x;   // block 128
    for (int k = t; k < 1024; k += 128) hr[k] = h[g*1024 + k];
    __syncthreads();
    float acc = bias[t];
    #pragma unroll 4
    for (int k = 0; k < 1024; ++k) acc += hr[k] * W[k*128 + t];
    out[g*128 + t] = acc;
}

// ---------------- RNA branch ----------------
__global__ void k_tok_count(const int* __restrict__ tok, int* tcnt, int S, int V){
    int id = blockIdx.x*256 + threadIdx.x;
    if (id >= NB*S) return;
    int b = id / S;
    atomicAdd(&tcnt[b*V + tok[id]], 1);
}

__global__ void k_tok_off(const int* __restrict__ tcnt, int* toff, int V){
    int b = blockIdx.x;
    if (threadIdx.x != 0) return;
    int run = 0;
    for (int v = 0; v < V; ++v){ toff[b*V + v] = run; run += tcnt[b*V + v]; }
}

__global__ void k_tok_scatter(const int* __restrict__ tok, const int* __restrict__ toff,
                              int* tcur, int* __restrict__ bucket, int S, int V){
    int id = blockIdx.x*256 + threadIdx.x;
    if (id >= NB*S) return;
    int b = id / S, c = id - b*S;
    int v = tok[id];
    int p = toff[b*V + v] + atomicAdd(&tcur[b*V + v], 1);
    bucket[b*S + p] = c;
}

// A[b,o,k,v] = sum_{c in bucket(b,v)} W[o,c,k]
__global__ void k_buildA(const float* __restrict__ W, const int* __restrict__ bucket,
                         const int* __restrict__ toff, const int* __restrict__ tcnt,
                         float* __restrict__ A, int S, int V){
    int bv = blockIdx.x;
    int b = bv / V, v = bv - b*V;
    int t = threadIdx.x;            // 256 = 32 o * 8 k
    int o = t >> 3, k = t & 7;
    const int* bk = bucket + b*S + toff[b*V + v];
    int m = tcnt[b*V + v];
    float acc = 0.f;
    int idx = 0;
    for (; idx + 4 <= m; idx += 4){
        int c0 = bk[idx], c1 = bk[idx+1], c2 = bk[idx+2], c3 = bk[idx+3];
        acc += W[(o*S + c0)*8 + k];
        acc += W[(o*S + c1)*8 + k];
        acc += W[(o*S + c2)*8 + k];
        acc += W[(o*S + c3)*8 + k];
    }
    for (; idx < m; ++idx) acc += W[(o*S + bk[idx])*8 + k];
    A[((b*32 + o)*8 + k)*V + v] = acc;
}

// ysum[b,o,l] = 0.5*(cb1[o]+cb2[o] + sum_{k,v} Ag*emb1[v,l+k] + sum_{k,v} Al*emb2[v,l+k])
__global__ void k_y(const float* __restrict__ Ag, const float* __restrict__ Al,
                    const float* __restrict__ emb1, const float* __restrict__ emb2,
                    const float* __restrict__ cb1, const float* __restrict__ cb2,
                    float* __restrict__ ysum){
    int bo = blockIdx.x;
    int b = bo >> 5, o = bo & 31;
    __shared__ float ag[8*VG], al[8*VL];
    int t = threadIdx.x;   // 128
    if (t < 8*VG) ag[t] = Ag[(b*32 + o)*(8*VG) + t];
    for (int idx = t; idx < 8*VL; idx += 128) al[idx] = Al[(b*32 + o)*(8*VL) + idx];
    __syncthreads();
    if (t >= 121) return;
    int l = t;
    float acc = cb1[o] + cb2[o];
    #pragma unroll
    for (int k = 0; k < 8; ++k){
        #pragma unroll
        for (int v = 0; v < VG; ++v) acc += ag[k*VG + v] * emb1[v*128 + l + k];
        for (int v = 0; v < VL; ++v) acc += al[k*VL + v] * emb2[v*128 + l + k];
    }
    ysum[b*3872 + o*121 + l] = 0.5f * acc;
}

// xc_rna[b,j] = sum_m ysum[b,m]*fcxrW[m,j] + fcxrb[j]
__global__ void k_fcxr(const float* __restrict__ ysum, const float* __restrict__ W,
                       const float* __restrict__ bias, float* __restrict__ out){
    __shared__ float yr[3872];
    int b = blockIdx.x, t = threadIdx.x;   // block 128
    for (int m = t; m < 3872; m += 128) yr[m] = ysum[b*3872 + m];
    __syncthreads();
    float acc = bias[t];
    #pragma unroll 4
    for (int m = 0; m < 3872; ++m) acc += yr[m] * W[m*128 + t];
    out[b*128 + t] = acc;
}

extern "C" void kernel_launch(void* const* d_in, const int* in_sizes, int n_in,
                              void* d_out, int out_size, void* d_ws, size_t ws_size,
                              hipStream_t stream)
{
    (void)in_sizes; (void)n_in; (void)out_size; (void)ws_size;

    const float* pro_x  = (const float*)d_in[0];
    const int*   eidx   = (const int*)  d_in[1];
    const float* ew     = (const float*)d_in[2];
    const int*   pbatch = (const int*)  d_in[3];
    const int*   rna_g  = (const int*)  d_in[4];
    const int*   rna_l  = (const int*)  d_in[5];
    const float* emb1   = (const float*)d_in[6];
    const float* emb2   = (const float*)d_in[7];
    const float* convW1 = (const float*)d_in[8];
    const float* convb1 = (const float*)d_in[9];
    const float* convW2 = (const float*)d_in[10];
    const float* convb2 = (const float*)d_in[11];
    const float* fcxrW  = (const float*)d_in[12];
    const float* fcxrb  = (const float*)d_in[13];
    const float* g1W = (const float*)d_in[14];
    const float* g1b = (const float*)d_in[15];
    const float* g2W = (const float*)d_in[16];
    const float* g2b = (const float*)d_in[17];
    const float* g3W = (const float*)d_in[18];
    const float* g3b = (const float*)d_in[19];
    const float* bn1g = (const float*)d_in[20];
    const float* bn1b = (const float*)d_in[21];
    const float* bn2g = (const float*)d_in[22];
    const float* bn2b = (const float*)d_in[23];
    const float* bn3g = (const float*)d_in[24];
    const float* bn3b = (const float*)d_in[25];
    const float* fcg1W = (const float*)d_in[26];
    const float* fcg1b = (const float*)d_in[27];
    const float* fcg2W = (const float*)d_in[28];
    const float* fcg2b = (const float*)d_in[29];

    const int* e_src = eidx;
    const int* e_dst = eidx + NE;

    char* base = (char*)d_ws;
    size_t off = 0;
    auto alloc = [&](size_t bytes)->char*{
        off = (off + 255) & ~(size_t)255;
        char* p = base + off; off += bytes; return p;
    };

    // ---- zero zone (single memset) ----
    int*   cnt     = (int*)  alloc(NN*4);
    float* degw    = (float*)alloc(NN*4);
    int*   cursor  = (int*)  alloc(NN*4);
    int*   tcnt_g  = (int*)  alloc(NB*VG*4);
    int*   tcur_g  = (int*)  alloc(NB*VG*4);
    int*   tcnt_l  = (int*)  alloc(NB*VL*4);
    int*   tcur_l  = (int*)  alloc(NB*VL*4);
    float* bnsum1  = (float*)alloc(2*33*4);
    float* bnsum2  = (float*)alloc(2*66*4);
    float* bnsum3  = (float*)alloc(2*132*4);
    float* poolsum = (float*)alloc(NG*132*4);
    float* cntg    = (float*)alloc(NG*4);
    size_t zero_bytes = (off + 255) & ~(size_t)255;

    // ---- persistent GCN-phase buffers ----
    float* dis1  = (float*)alloc(NN*4);
    float* dis2  = (float*)alloc(NN*4);
    float* self1 = (float*)alloc(NN*4);
    float* self2 = (float*)alloc(NN*4);
    int*   offs  = (int*)  alloc(NN*4);
    int*   bsum  = (int*)  alloc(64*4);
    int*   esrc  = (int*)  alloc(NE*4);
    float* en1   = (float*)alloc(NE*4);
    float* en2   = (float*)alloc(NE*4);
    float* bnscale = (float*)alloc(132*4);
    float* bnshift = (float*)alloc(132*4);
    float* h     = (float*)alloc(NG*1024*4);
    float* bufA  = (float*)alloc((size_t)NN*132*4);
    float* bufB  = (float*)alloc((size_t)NN*132*4);

    // ---- RNA-phase scratch: aliased onto bufA/bufB (RNA kernels all
    // complete before the first k_agg writes bufA — same stream) ----
    {
        char* rb = (char*)bufA;
        size_t ro = 0;
        auto ralloc = [&](size_t bytes)->char*{
            ro = (ro + 255) & ~(size_t)255;
            char* p = rb + ro; ro += bytes; return p;
        };
        int* toff_g   = (int*)ralloc(NB*VG*4);
        int* toff_l   = (int*)ralloc(NB*VL*4);
        int* bucket_g = (int*)ralloc((size_t)NB*SG*4);
        int* bucket_l = (int*)ralloc((size_t)NB*SL*4);
        float* Ag     = (float*)ralloc((size_t)NB*32*8*VG*4);
        float* Al     = (float*)ralloc((size_t)NB*32*8*VL*4);
        float* ysum   = (float*)ralloc((size_t)NB*3872*4);

        hipMemsetAsync(d_ws, 0, zero_bytes, stream);

        float* out0 = (float*)d_out;          // xc_rna

        // ---------------- RNA branch ----------------
        k_tok_count<<<(NB*SG+255)/256, 256, 0, stream>>>(rna_g, tcnt_g, SG, VG);
        k_tok_count<<<(NB*SL+255)/256, 256, 0, stream>>>(rna_l, tcnt_l, SL, VL);
        k_tok_off<<<NB, 64, 0, stream>>>(tcnt_g, toff_g, VG);
        k_tok_off<<<NB, 64, 0, stream>>>(tcnt_l, toff_l, VL);
        k_tok_scatter<<<(NB*SG+255)/256, 256, 0, stream>>>(rna_g, toff_g, tcur_g, bucket_g, SG, VG);
        k_tok_scatter<<<(NB*SL+255)/256, 256, 0, stream>>>(rna_l, toff_l, tcur_l, bucket_l, SL, VL);
        k_buildA<<<NB*VG, 256, 0, stream>>>(convW1, bucket_g, toff_g, tcnt_g, Ag, SG, VG);
        k_buildA<<<NB*VL, 256, 0, stream>>>(convW2, bucket_l, toff_l, tcnt_l, Al, SL, VL);
        k_y<<<NB*32, 128, 0, stream>>>(Ag, Al, emb1, emb2, convb1, convb2, ysum);
        k_fcxr<<<NB, 128, 0, stream>>>(ysum, fcxrW, fcxrb, out0);
    }

    float* out1 = (float*)d_out + 16384;  // xp_out

    // ---------------- graph prep ----------------
    k_edge_deg<<<(NE+255)/256, 256, 0, stream>>>(e_dst, ew, cnt, degw);
    k_node_dis<<<(NN+255)/256, 256, 0, stream>>>(cnt, degw, dis1, dis2, self1, self2);
    k_scan1<<<49, 256, 0, stream>>>(cnt, bsum);
    k_scan2<<<1, 64, 0, stream>>>(bsum, 49);
    k_scan3<<<49, 256, 0, stream>>>(cnt, bsum, offs);
    k_edge_scatter<<<(NE+255)/256, 256, 0, stream>>>(e_src, e_dst, ew, dis1, dis2,
                                                     offs, cursor, esrc, en1, en2);

    // ---------------- GCN layer 1 (33 -> 33) ----------------
    k_agg<<<NN, 64, 0, stream>>>(pro_x, esrc, en1, offs, cnt, self1, bufA, 33);
    k_gemm_node<<<NN, 64, 0, stream>>>(bufA, g1W, g1b, bufB, 33, 33);
    k_bn_stats<<<256, 64, 0, stream>>>(bufB, bnsum1, 33);
    k_bn_finalize<<<1, 192, 0, stream>>>(bnsum1, bn1g, bn1b, bnscale, bnshift, 33);
    k_bn_apply<<<NN, 64, 0, stream>>>(bufB, bnscale, bnshift, bufA, 33);

    // ---------------- GCN layer 2 (33 -> 66) ----------------
    k_agg<<<NN, 64, 0, stream>>>(bufA, esrc, en2, offs, cnt, self2, bufB, 33);
    k_gemm_node<<<NN, 128, 0, stream>>>(bufB, g2W, g2b, bufA, 33, 66);
    k_bn_stats<<<256, 128, 0, stream>>>(bufA, bnsum2, 66);
    k_bn_finalize<<<1, 192, 0, stream>>>(bnsum2, bn2g, bn2b, bnscale, bnshift, 66);
    k_bn_apply<<<NN, 128, 0, stream>>>(bufA, bnscale, bnshift, bufB, 66);

    // ---------------- GCN layer 3 (66 -> 132) ----------------
    k_agg<<<NN, 128, 0, stream>>>(bufB, esrc, en2, offs, cnt, self2, bufA, 66);
    k_gemm_node<<<NN, 192, 0, stream>>>(bufA, g3W, g3b, bufB, 66, 132);
    k_bn_stats<<<256, 192, 0, stream>>>(bufB, bnsum3, 132);
    k_bn_finalize<<<1, 192, 0, stream>>>(bnsum3, bn3g, bn3b, bnscale, bnshift, 132);
    k_bn_apply<<<NN, 192, 0, stream>>>(bufB, bnscale, bnshift, bufA, 132);

    // ---------------- pool + head ----------------
    k_pool_cnt<<<(NN+255)/256, 256, 0, stream>>>(pbatch, cntg);
    k_pool_sum<<<(NN*132+255)/256, 256, 0, stream>>>(bufA, pbatch, poolsum);
    k_fcg1<<<NG, 256, 0, stream>>>(poolsum, cntg, fcg1W, fcg1b, h);
    k_fcg2<<<NG, 128, 0, stream>>>(h, fcg2W, fcg2b, out1);
}

// Round 3
// 1226.753 us; speedup vs baseline: 2.2471x; 2.2471x over previous
//
#include <hip/hip_runtime.h>
#include <hip/hip_bf16.h>

#define NN 50000      // nodes
#define NE 1600000    // edges
#define NG 128        // graphs
#define NB 128        // rna batch
#define SG 3000       // global seq (channels)
#define SL 2998       // local seq
#define VG 5          // global vocab
#define VL 65         // local vocab

// ---------------- graph prep ----------------
__global__ void k_edge_deg(const int* __restrict__ dst, const float* __restrict__ ew,
                           int* cnt, float* degw){
    int e = blockIdx.x*256 + threadIdx.x;
    if (e >= NE) return;
    int d = dst[e];
    atomicAdd(&cnt[d], 1);
    atomicAdd(&degw[d], ew[e]);
}

__global__ void k_node_dis(const int* __restrict__ cnt, const float* __restrict__ degw,
                           float* dis1, float* dis2, float* self1, float* self2){
    int i = blockIdx.x*256 + threadIdx.x;
    if (i >= NN) return;
    float d1 = degw[i] + 1.0f;
    float r1 = rsqrtf(d1);
    dis1[i] = r1; self1[i] = r1*r1;
    float d2 = (float)cnt[i] + 1.0f;
    float r2 = rsqrtf(d2);
    dis2[i] = r2; self2[i] = r2*r2;
}

__global__ void k_scan1(const int* __restrict__ cnt, int* bsum){
    __shared__ int sd[256];
    int t = threadIdx.x;
    int base = blockIdx.x*1024;
    int s = 0;
    #pragma unroll
    for (int j = 0; j < 4; ++j){
        int idx = base + t*4 + j;
        if (idx < NN) s += cnt[idx];
    }
    sd[t] = s; __syncthreads();
    for (int d = 128; d > 0; d >>= 1){
        if (t < d) sd[t] += sd[t+d];
        __syncthreads();
    }
    if (t == 0) bsum[blockIdx.x] = sd[0];
}

__global__ void k_scan2(int* bsum, int nb){
    if (threadIdx.x == 0 && blockIdx.x == 0){
        int run = 0;
        for (int i = 0; i < nb; ++i){ int v = bsum[i]; bsum[i] = run; run += v; }
    }
}

__global__ void k_scan3(const int* __restrict__ cnt, const int* __restrict__ bsum,
                        int* __restrict__ offs){
    __shared__ int sd[256];
    int t = threadIdx.x;
    int base = blockIdx.x*1024;
    int loc[4]; int s = 0;
    #pragma unroll
    for (int j = 0; j < 4; ++j){
        int idx = base + t*4 + j;
        loc[j] = (idx < NN) ? cnt[idx] : 0;
        s += loc[j];
    }
    sd[t] = s; __syncthreads();
    for (int d = 1; d < 256; d <<= 1){
        int v = (t >= d) ? sd[t-d] : 0;
        __syncthreads();
        sd[t] += v;
        __syncthreads();
    }
    int run = bsum[blockIdx.x] + (sd[t] - s);
    #pragma unroll
    for (int j = 0; j < 4; ++j){
        int idx = base + t*4 + j;
        if (idx < NN) offs[idx] = run;
        run += loc[j];
    }
}

__global__ void k_edge_scatter(const int* __restrict__ src, const int* __restrict__ dst,
                               const float* __restrict__ ew,
                               const float* __restrict__ dis1, const float* __restrict__ dis2,
                               const int* __restrict__ offs, int* cursor,
                               int* __restrict__ esrc, float* __restrict__ en1,
                               float* __restrict__ en2){
    int e = blockIdx.x*256 + threadIdx.x;
    if (e >= NE) return;
    int s = src[e], d = dst[e];
    int p = offs[d] + atomicAdd(&cursor[d], 1);
    esrc[p] = s;
    en1[p] = dis1[s] * ew[e] * dis1[d];
    en2[p] = dis2[s] * dis2[d];
}

// agg[i,f] = selfw[i]*x[i,f] + sum_e norm[e]*x[src_e,f]   (aggregate BEFORE W)
__global__ void k_agg(const float* __restrict__ x, const int* __restrict__ esrc,
                      const float* __restrict__ en, const int* __restrict__ offs,
                      const int* __restrict__ cnt, const float* __restrict__ selfw,
                      float* __restrict__ agg, int F){
    int i = blockIdx.x;
    int f = threadIdx.x;
    if (f >= F) return;
    float acc = selfw[i] * x[i*F + f];
    int b = offs[i];
    int e = b + cnt[i];
    int p = b;
    for (; p + 4 <= e; p += 4){
        int s0 = esrc[p], s1 = esrc[p+1], s2 = esrc[p+2], s3 = esrc[p+3];
        float n0 = en[p], n1 = en[p+1], n2 = en[p+2], n3 = en[p+3];
        float v0 = x[s0*F + f];
        float v1 = x[s1*F + f];
        float v2 = x[s2*F + f];
        float v3 = x[s3*F + f];
        acc += n0*v0; acc += n1*v1; acc += n2*v2; acc += n3*v3;
    }
    for (; p < e; ++p) acc += en[p] * x[esrc[p]*F + f];
    agg[i*F + f] = acc;
}

// 8 nodes per block; W row loaded once, used for 8 nodes.
__global__ void k_gemm_node8(const float* __restrict__ x, const float* __restrict__ W,
                             const float* __restrict__ bias, float* __restrict__ out,
                             int F, int OF){
    extern __shared__ float xs[];   // 8*F floats
    int i0 = blockIdx.x * 8;
    int t = threadIdx.x;
    for (int idx = t; idx < 8*F; idx += blockDim.x){
        int r = idx / F, f = idx - r*F;
        xs[r*F + f] = x[(i0 + r)*F + f];
    }
    __syncthreads();
    if (t >= OF) return;
    float acc0, acc1, acc2, acc3, acc4, acc5, acc6, acc7;
    float bj = bias[t];
    acc0=bj; acc1=bj; acc2=bj; acc3=bj; acc4=bj; acc5=bj; acc6=bj; acc7=bj;
    for (int f = 0; f < F; ++f){
        float w = W[f*OF + t];
        acc0 += xs[0*F+f]*w; acc1 += xs[1*F+f]*w;
        acc2 += xs[2*F+f]*w; acc3 += xs[3*F+f]*w;
        acc4 += xs[4*F+f]*w; acc5 += xs[5*F+f]*w;
        acc6 += xs[6*F+f]*w; acc7 += xs[7*F+f]*w;
    }
    out[(i0+0)*OF + t] = acc0; out[(i0+1)*OF + t] = acc1;
    out[(i0+2)*OF + t] = acc2; out[(i0+3)*OF + t] = acc3;
    out[(i0+4)*OF + t] = acc4; out[(i0+5)*OF + t] = acc5;
    out[(i0+6)*OF + t] = acc6; out[(i0+7)*OF + t] = acc7;
}

__global__ void k_bn_stats(const float* __restrict__ t, float* __restrict__ sums, int OF){
    int f = threadIdx.x;
    if (f >= OF) return;
    float s = 0.f, ss = 0.f;
    for (int i = blockIdx.x; i < NN; i += gridDim.x){
        float v = t[i*OF + f];
        s += v; ss += v*v;
    }
    atomicAdd(&sums[f], s);
    atomicAdd(&sums[OF + f], ss);
}

__global__ void k_bn_finalize(const float* __restrict__ sums, const float* __restrict__ g,
                              const float* __restrict__ b, float* scale, float* shift, int OF){
    int f = threadIdx.x;
    if (f >= OF) return;
    float m = sums[f] / (float)NN;
    float v = sums[OF + f] / (float)NN - m*m;
    float sc = g[f] * rsqrtf(v + 1e-5f);
    scale[f] = sc;
    shift[f] = b[f] - m*sc;
}

__global__ void k_bn_apply(const float* __restrict__ t, const float* __restrict__ scale,
                           const float* __restrict__ shift, float* __restrict__ xo, int OF){
    int i = blockIdx.x, f = threadIdx.x;
    if (f >= OF) return;
    float v = t[i*OF + f] * scale[f] + shift[f];
    xo[i*OF + f] = v > 0.f ? v : 0.f;
}

// ---- pooling via sorted pro_batch: boundary scan, no atomics ----
// gstart[g] = first node index with batch >= g ; gstart[G] = NN
__global__ void k_gbounds(const int* __restrict__ batch, int* __restrict__ gstart){
    int i = blockIdx.x*256 + threadIdx.x;
    if (i >= NN) return;
    int pb = batch[i];
    int prev = (i == 0) ? -1 : batch[i-1];
    for (int g = prev + 1; g <= pb; ++g) gstart[g] = i;
    if (i == NN - 1){
        for (int g = pb + 1; g <= NG; ++g) gstart[g] = NN;
    }
}

__global__ void k_poolg(const float* __restrict__ x, const int* __restrict__ gstart,
                        float* __restrict__ pooled){
    int g = blockIdx.x, f = threadIdx.x;
    if (f >= 132) return;
    int i0 = gstart[g], i1 = gstart[g+1];
    float s = 0.f;
    for (int i = i0; i < i1; ++i) s += x[i*132 + f];
    float inv = 1.0f / fmaxf((float)(i1 - i0), 1.0f);
    pooled[g*132 + f] = s * inv;
}

__global__ void k_fcg1(const float* __restrict__ pooled,
                       const float* __restrict__ W, const float* __restrict__ bias,
                       float* __restrict__ h){
    __shared__ float pr[132];
    int g = blockIdx.x, t = threadIdx.x;
    if (t < 132) pr[t] = pooled[g*132 + t];
    __syncthreads();
    for (int j = t; j < 1024; j += blockDim.x){
        float acc = bias[j];
        #pragma unroll 4
        for (int f = 0; f < 132; ++f) acc += pr[f] * W[f*1024 + j];
        h[g*1024 + j] = acc > 0.f ? acc : 0.f;
    }
}

__global__ void k_fcg2(const float* __restrict__ h, const float* __restrict__ W,
                       const float* __restrict__ bias, float* __restrict__ out){
    __shared__ float hr[1024];
    int g = blockIdx.x, t = threadIdx.x;   // block 128
    for (int k = t; k < 1024; k += 128) hr[k] = h[g*1024 + k];
    __syncthreads();
    float acc = bias[t];
    #pragma unroll 4
    for (int k = 0; k < 1024; ++k) acc += hr[k] * W[k*128 + t];
    out[g*128 + t] = acc;
}

// ---------------- RNA branch ----------------
#define CH 12   // ceil(S/256) for both S=3000 and 2998

__global__ void k_tok_count(const int* __restrict__ tok, int* tcnt, int S, int V){
    __shared__ int lh[VL];
    int b = blockIdx.x / CH, c0 = (blockIdx.x % CH)*256;
    int t = threadIdx.x;
    if (t < V) lh[t] = 0;
    __syncthreads();
    int i = c0 + t;
    if (i < S) atomicAdd(&lh[tok[b*S + i]], 1);
    __syncthreads();
    if (t < V && lh[t] > 0) atomicAdd(&tcnt[b*V + t], lh[t]);
}

__global__ void k_tok_off(const int* __restrict__ tcnt, int* toff, int V){
    int b = blockIdx.x;
    if (threadIdx.x != 0) return;
    int run = 0;
    for (int v = 0; v < V; ++v){ toff[b*V + v] = run; run += tcnt[b*V + v]; }
}

__global__ void k_tok_scatter(const int* __restrict__ tok, const int* __restrict__ toff,
                              int* tcur, int* __restrict__ bucket, int S, int V){
    __shared__ int lh[VL], lbase[VL], lcur[VL];
    int b = blockIdx.x / CH, c0 = (blockIdx.x % CH)*256;
    int t = threadIdx.x;
    if (t < V){ lh[t] = 0; lcur[t] = 0; }
    __syncthreads();
    int i = c0 + t;
    int v = -1;
    if (i < S){ v = tok[b*S + i]; atomicAdd(&lh[v], 1); }
    __syncthreads();
    if (t < V && lh[t] > 0) lbase[t] = atomicAdd(&tcur[b*V + t], lh[t]);
    __syncthreads();
    if (i < S){
        int p = lbase[v] + atomicAdd(&lcur[v], 1);
        bucket[b*S + toff[b*V + v] + p] = i;
    }
}

// Wr[c*256 + o*8 + k] = W[(o*S + c)*8 + k]   (coalesced bucket reads)
__global__ void k_transposeW(const float* __restrict__ W, float* __restrict__ Wr, int S){
    int c = blockIdx.x, t = threadIdx.x;
    Wr[c*256 + t] = W[((t >> 3)*S + c)*8 + (t & 7)];
}

// A[b*256V + (o*8+k)*V + v] = sum_{c in bucket(b,v)} Wr[c*256 + o*8+k]
__global__ void k_buildA(const float* __restrict__ Wr, const int* __restrict__ bucket,
                         const int* __restrict__ toff, const int* __restrict__ tcnt,
                         float* __restrict__ A, int S, int V){
    int bv = blockIdx.x;
    int b = bv / V, v = bv - b*V;
    int t = threadIdx.x;            // t = o*8+k
    const int* bk = bucket + b*S + toff[b*V + v];
    int m = tcnt[b*V + v];
    float acc = 0.f;
    int idx = 0;
    for (; idx + 4 <= m; idx += 4){
        int c0 = bk[idx], c1 = bk[idx+1], c2 = bk[idx+2], c3 = bk[idx+3];
        acc += Wr[c0*256 + t];
        acc += Wr[c1*256 + t];
        acc += Wr[c2*256 + t];
        acc += Wr[c3*256 + t];
    }
    for (; idx < m; ++idx) acc += Wr[bk[idx]*256 + t];
    A[b*(256*V) + t*V + v] = acc;
}

// G[(o*M + m)*128 + j] = sum_l emb[v,l+k] * fcxrW[(o*121+l)*128 + j],  m=k*V+v, M=8V
__global__ void k_buildG(const float* __restrict__ emb, const float* __restrict__ W,
                         float* __restrict__ G, int V, int MT4){
    __shared__ float rows[4][128];
    int o = blockIdx.x / MT4, mt = blockIdx.x % MT4;
    int t = threadIdx.x;   // 128, j
    int kk[4];
    #pragma unroll
    for (int mm = 0; mm < 4; ++mm){
        int m = mt*4 + mm;
        int k = m / V, v = m - k*V;
        kk[mm] = k;
        rows[mm][t] = emb[v*128 + t];
    }
    __syncthreads();
    float a0 = 0.f, a1 = 0.f, a2 = 0.f, a3 = 0.f;
    const float* Wo = W + o*121*128 + t;
    for (int l = 0; l < 121; ++l){
        float w = Wo[l*128];
        a0 += rows[0][l + kk[0]] * w;
        a1 += rows[1][l + kk[1]] * w;
        a2 += rows[2][l + kk[2]] * w;
        a3 += rows[3][l + kk[3]] * w;
    }
    int M = 8*V;
    int base = (o*M + mt*4)*128 + t;
    G[base        ] = a0;
    G[base + 128  ] = a1;
    G[base + 256  ] = a2;
    G[base + 384  ] = a3;
}

__global__ void k_bias0_init(const float* __restrict__ fcxrb, float* __restrict__ bias0){
    bias0[threadIdx.x] = fcxrb[threadIdx.x];
}

__global__ void k_bias0_acc(const float* __restrict__ W, const float* __restrict__ cb1,
                            const float* __restrict__ cb2, float* __restrict__ bias0){
    int o = blockIdx.x, j = threadIdx.x;
    float s = 0.f;
    const float* Wo = W + o*121*128 + j;
    for (int l = 0; l < 121; ++l) s += Wo[l*128];
    atomicAdd(&bias0[j], 0.5f * (cb1[o] + cb2[o]) * s);
}

__global__ void k_init_out0(const float* __restrict__ bias0, float* __restrict__ out0){
    out0[blockIdx.x*128 + threadIdx.x] = bias0[threadIdx.x];
}

// out0[b,j] += 0.5 * sum_k X[b,k]*G[k,j]   (split-K, 8 b-rows per block)
__global__ void k_gemmR(const float* __restrict__ X, const float* __restrict__ G,
                        float* __restrict__ out0, int K){
    __shared__ float xs[8][256];
    int b0 = blockIdx.x * 8;
    int k0 = blockIdx.y * 256;
    int t = threadIdx.x;   // 128, j
    #pragma unroll
    for (int r = 0; r < 8; ++r){
        xs[r][t]       = X[(b0+r)*K + k0 + t];
        xs[r][t + 128] = X[(b0+r)*K + k0 + t + 128];
    }
    __syncthreads();
    float a0=0,a1=0,a2=0,a3=0,a4=0,a5=0,a6=0,a7=0;
    const float* Gp = G + (size_t)k0*128 + t;
    for (int kk = 0; kk < 256; ++kk){
        float g = Gp[kk*128];
        a0 += xs[0][kk]*g; a1 += xs[1][kk]*g;
        a2 += xs[2][kk]*g; a3 += xs[3][kk]*g;
        a4 += xs[4][kk]*g; a5 += xs[5][kk]*g;
        a6 += xs[6][kk]*g; a7 += xs[7][kk]*g;
    }
    atomicAdd(&out0[(b0+0)*128 + t], 0.5f*a0);
    atomicAdd(&out0[(b0+1)*128 + t], 0.5f*a1);
    atomicAdd(&out0[(b0+2)*128 + t], 0.5f*a2);
    atomicAdd(&out0[(b0+3)*128 + t], 0.5f*a3);
    atomicAdd(&out0[(b0+4)*128 + t], 0.5f*a4);
    atomicAdd(&out0[(b0+5)*128 + t], 0.5f*a5);
    atomicAdd(&out0[(b0+6)*128 + t], 0.5f*a6);
    atomicAdd(&out0[(b0+7)*128 + t], 0.5f*a7);
}

extern "C" void kernel_launch(void* const* d_in, const int* in_sizes, int n_in,
                              void* d_out, int out_size, void* d_ws, size_t ws_size,
                              hipStream_t stream)
{
    (void)in_sizes; (void)n_in; (void)out_size; (void)ws_size;

    const float* pro_x  = (const float*)d_in[0];
    const int*   eidx   = (const int*)  d_in[1];
    const float* ew     = (const float*)d_in[2];
    const int*   pbatch = (const int*)  d_in[3];
    const int*   rna_g  = (const int*)  d_in[4];
    const int*   rna_l  = (const int*)  d_in[5];
    const float* emb1   = (const float*)d_in[6];
    const float* emb2   = (const float*)d_in[7];
    const float* convW1 = (const float*)d_in[8];
    const float* convb1 = (const float*)d_in[9];
    const float* convW2 = (const float*)d_in[10];
    const float* convb2 = (const float*)d_in[11];
    const float* fcxrW  = (const float*)d_in[12];
    const float* fcxrb  = (const float*)d_in[13];
    const float* g1W = (const float*)d_in[14];
    const float* g1b = (const float*)d_in[15];
    const float* g2W = (const float*)d_in[16];
    const float* g2b = (const float*)d_in[17];
    const float* g3W = (const float*)d_in[18];
    const float* g3b = (const float*)d_in[19];
    const float* bn1g = (const float*)d_in[20];
    const float* bn1b = (const float*)d_in[21];
    const float* bn2g = (const float*)d_in[22];
    const float* bn2b = (const float*)d_in[23];
    const float* bn3g = (const float*)d_in[24];
    const float* bn3b = (const float*)d_in[25];
    const float* fcg1W = (const float*)d_in[26];
    const float* fcg1b = (const float*)d_in[27];
    const float* fcg2W = (const float*)d_in[28];
    const float* fcg2b = (const float*)d_in[29];

    const int* e_src = eidx;
    const int* e_dst = eidx + NE;

    char* base = (char*)d_ws;
    size_t off = 0;
    auto alloc = [&](size_t bytes)->char*{
        off = (off + 255) & ~(size_t)255;
        char* p = base + off; off += bytes; return p;
    };

    // ---- zero zone (single memset) ----
    int*   cnt     = (int*)  alloc(NN*4);
    float* degw    = (float*)alloc(NN*4);
    int*   cursor  = (int*)  alloc(NN*4);
    int*   tcnt_g  = (int*)  alloc(NB*VG*4);
    int*   tcur_g  = (int*)  alloc(NB*VG*4);
    int*   tcnt_l  = (int*)  alloc(NB*VL*4);
    int*   tcur_l  = (int*)  alloc(NB*VL*4);
    float* bnsum1  = (float*)alloc(2*33*4);
    float* bnsum2  = (float*)alloc(2*66*4);
    float* bnsum3  = (float*)alloc(2*132*4);
    size_t zero_bytes = (off + 255) & ~(size_t)255;

    // ---- persistent GCN-phase buffers ----
    float* dis1  = (float*)alloc(NN*4);
    float* dis2  = (float*)alloc(NN*4);
    float* self1 = (float*)alloc(NN*4);
    float* self2 = (float*)alloc(NN*4);
    int*   offs  = (int*)  alloc(NN*4);
    int*   bsum  = (int*)  alloc(64*4);
    int*   esrc  = (int*)  alloc(NE*4);
    float* en1   = (float*)alloc(NE*4);
    float* en2   = (float*)alloc(NE*4);
    float* bnscale = (float*)alloc(132*4);
    float* bnshift = (float*)alloc(132*4);
    float* h     = (float*)alloc(NG*1024*4);
    float* pooled= (float*)alloc(NG*132*4);
    int*   gstart= (int*)  alloc((NG+1)*4);
    float* bufA  = (float*)alloc((size_t)NN*132*4);
    float* bufB  = (float*)alloc((size_t)NN*132*4);

    float* out0 = (float*)d_out;          // xc_rna
    float* out1 = (float*)d_out + 16384;  // xp_out

    // ---- RNA-phase scratch aliased onto bufA/bufB (RNA completes before
    // the first k_agg writes bufA; same stream serializes) ----
    {
        char* rb = (char*)bufA;
        size_t ro = 0;
        auto ralloc = [&](size_t bytes)->char*{
            ro = (ro + 255) & ~(size_t)255;
            char* p = rb + ro; ro += bytes; return p;
        };
        int* toff_g   = (int*)ralloc(NB*VG*4);
        int* toff_l   = (int*)ralloc(NB*VL*4);
        int* bucket_g = (int*)ralloc((size_t)NB*SG*4);
        int* bucket_l = (int*)ralloc((size_t)NB*SL*4);
        float* Wr1    = (float*)ralloc((size_t)SG*256*4);
        float* Wr2    = (float*)ralloc((size_t)SL*256*4);
        float* Ag     = (float*)ralloc((size_t)NB*256*VG*4);
        float* Al     = (float*)ralloc((size_t)NB*256*VL*4);
        float* G1     = (float*)ralloc((size_t)32*8*VG*128*4);
        float* G2     = (float*)ralloc((size_t)32*8*VL*128*4);
        float* bias0  = (float*)ralloc(128*4);

        hipMemsetAsync(d_ws, 0, zero_bytes, stream);

        // token bucketing
        k_tok_count<<<NB*CH, 256, 0, stream>>>(rna_g, tcnt_g, SG, VG);
        k_tok_count<<<NB*CH, 256, 0, stream>>>(rna_l, tcnt_l, SL, VL);
        k_tok_off<<<NB, 64, 0, stream>>>(tcnt_g, toff_g, VG);
        k_tok_off<<<NB, 64, 0, stream>>>(tcnt_l, toff_l, VL);
        k_tok_scatter<<<NB*CH, 256, 0, stream>>>(rna_g, toff_g, tcur_g, bucket_g, SG, VG);
        k_tok_scatter<<<NB*CH, 256, 0, stream>>>(rna_l, toff_l, tcur_l, bucket_l, SL, VL);
        // conv weight transpose + bucketed A
        k_transposeW<<<SG, 256, 0, stream>>>(convW1, Wr1, SG);
        k_transposeW<<<SL, 256, 0, stream>>>(convW2, Wr2, SL);
        k_buildA<<<NB*VG, 256, 0, stream>>>(Wr1, bucket_g, toff_g, tcnt_g, Ag, SG, VG);
        k_buildA<<<NB*VL, 256, 0, stream>>>(Wr2, bucket_l, toff_l, tcnt_l, Al, SL, VL);
        // fold emb into fcxr weight
        k_buildG<<<32*(8*VG/4), 128, 0, stream>>>(emb1, fcxrW, G1, VG, 8*VG/4);
        k_buildG<<<32*(8*VL/4), 128, 0, stream>>>(emb2, fcxrW, G2, VL, 8*VL/4);
        k_bias0_init<<<1, 128, 0, stream>>>(fcxrb, bias0);
        k_bias0_acc<<<32, 128, 0, stream>>>(fcxrW, convb1, convb2, bias0);
        k_init_out0<<<NB, 128, 0, stream>>>(bias0, out0);
        // out0 = bias0 + 0.5*(Ag·G1 + Al·G2)
        k_gemmR<<<dim3(16, (8*VG*32)/256), 128, 0, stream>>>(Ag, G1, out0, 8*VG*32);
        k_gemmR<<<dim3(16, (8*VL*32)/256), 128, 0, stream>>>(Al, G2, out0, 8*VL*32);
    }

    // ---------------- graph prep ----------------
    k_edge_deg<<<(NE+255)/256, 256, 0, stream>>>(e_dst, ew, cnt, degw);
    k_node_dis<<<(NN+255)/256, 256, 0, stream>>>(cnt, degw, dis1, dis2, self1, self2);
    k_scan1<<<49, 256, 0, stream>>>(cnt, bsum);
    k_scan2<<<1, 64, 0, stream>>>(bsum, 49);
    k_scan3<<<49, 256, 0, stream>>>(cnt, bsum, offs);
    k_edge_scatter<<<(NE+255)/256, 256, 0, stream>>>(e_src, e_dst, ew, dis1, dis2,
                                                     offs, cursor, esrc, en1, en2);

    // ---------------- GCN layer 1 (33 -> 33) ----------------
    k_agg<<<NN, 64, 0, stream>>>(pro_x, esrc, en1, offs, cnt, self1, bufA, 33);
    k_gemm_node8<<<NN/8, 64, 8*33*4, stream>>>(bufA, g1W, g1b, bufB, 33, 33);
    k_bn_stats<<<256, 64, 0, stream>>>(bufB, bnsum1, 33);
    k_bn_finalize<<<1, 192, 0, stream>>>(bnsum1, bn1g, bn1b, bnscale, bnshift, 33);
    k_bn_apply<<<NN, 64, 0, stream>>>(bufB, bnscale, bnshift, bufA, 33);

    // ---------------- GCN layer 2 (33 -> 66) ----------------
    k_agg<<<NN, 64, 0, stream>>>(bufA, esrc, en2, offs, cnt, self2, bufB, 33);
    k_gemm_node8<<<NN/8, 128, 8*33*4, stream>>>(bufB, g2W, g2b, bufA, 33, 66);
    k_bn_stats<<<256, 128, 0, stream>>>(bufA, bnsum2, 66);
    k_bn_finalize<<<1, 192, 0, stream>>>(bnsum2, bn2g, bn2b, bnscale, bnshift, 66);
    k_bn_apply<<<NN, 128, 0, stream>>>(bufA, bnscale, bnshift, bufB, 66);

    // ---------------- GCN layer 3 (66 -> 132) ----------------
    k_agg<<<NN, 128, 0, stream>>>(bufB, esrc, en2, offs, cnt, self2, bufA, 66);
    k_gemm_node8<<<NN/8, 192, 8*66*4, stream>>>(bufA, g3W, g3b, bufB, 66, 132);
    k_bn_stats<<<256, 192, 0, stream>>>(bufB, bnsum3, 132);
    k_bn_finalize<<<1, 192, 0, stream>>>(bnsum3, bn3g, bn3b, bnscale, bnshift, 132);
    k_bn_apply<<<NN, 192, 0, stream>>>(bufB, bnscale, bnshift, bufA, 132);

    // ---------------- pool + head ----------------
    k_gbounds<<<(NN+255)/256, 256, 0, stream>>>(pbatch, gstart);
    k_poolg<<<NG, 192, 0, stream>>>(bufA, gstart, pooled);
    k_fcg1<<<NG, 256, 0, stream>>>(pooled, fcg1W, fcg1b, h);
    k_fcg2<<<NG, 128, 0, stream>>>(h, fcg2W, fcg2b, out1);
}

// Round 4
// 1151.602 us; speedup vs baseline: 2.3937x; 1.0653x over previous
//
#include <hip/hip_runtime.h>
#include <hip/hip_bf16.h>

typedef __hip_bfloat16 bf16;

#define NN 50000      // nodes
#define NE 1600000    // edges
#define NG 128        // graphs
#define NB 128        // rna batch
#define SG 3000       // global seq (channels)
#define SL 2998       // local seq
#define VG 5          // global vocab
#define VL 65         // local vocab

__device__ __forceinline__ float b2f(bf16 x){ return __bfloat162float(x); }

// ---------------- graph prep ----------------
// packed[d] += 2^20 + ew  (count in high bits, weighted degree in low).
// Returned old value gives this edge's slot within d's CSR segment.
__global__ void k_edge_deg(const int* __restrict__ dst, const float* __restrict__ ew,
                           double* __restrict__ packed, int* __restrict__ slot){
    int e = blockIdx.x*256 + threadIdx.x;
    if (e >= NE) return;
    double old = atomicAdd(&packed[dst[e]], 1048576.0 + (double)ew[e]);
    slot[e] = (int)(old * (1.0/1048576.0));
}

__global__ void k_node_dis(const double* __restrict__ packed, int* __restrict__ cnt,
                           float2* __restrict__ dis12, float2* __restrict__ self12){
    int i = blockIdx.x*256 + threadIdx.x;
    if (i >= NN) return;
    double p = packed[i];
    int c = (int)(p * (1.0/1048576.0));
    float w = (float)(p - (double)c * 1048576.0);
    cnt[i] = c;
    float r1 = rsqrtf(w + 1.0f);
    float r2 = rsqrtf((float)c + 1.0f);
    dis12[i] = make_float2(r1, r2);
    self12[i] = make_float2(r1*r1, r2*r2);
}

__global__ void k_scan1(const int* __restrict__ cnt, int* bsum){
    __shared__ int sd[256];
    int t = threadIdx.x;
    int base = blockIdx.x*1024;
    int s = 0;
    #pragma unroll
    for (int j = 0; j < 4; ++j){
        int idx = base + t*4 + j;
        if (idx < NN) s += cnt[idx];
    }
    sd[t] = s; __syncthreads();
    for (int d = 128; d > 0; d >>= 1){
        if (t < d) sd[t] += sd[t+d];
        __syncthreads();
    }
    if (t == 0) bsum[blockIdx.x] = sd[0];
}

__global__ void k_scan2(int* bsum, int nb){
    if (threadIdx.x == 0 && blockIdx.x == 0){
        int run = 0;
        for (int i = 0; i < nb; ++i){ int v = bsum[i]; bsum[i] = run; run += v; }
    }
}

__global__ void k_scan3(const int* __restrict__ cnt, const int* __restrict__ bsum,
                        int* __restrict__ offs){
    __shared__ int sd[256];
    int t = threadIdx.x;
    int base = blockIdx.x*1024;
    int loc[4]; int s = 0;
    #pragma unroll
    for (int j = 0; j < 4; ++j){
        int idx = base + t*4 + j;
        loc[j] = (idx < NN) ? cnt[idx] : 0;
        s += loc[j];
    }
    sd[t] = s; __syncthreads();
    for (int d = 1; d < 256; d <<= 1){
        int v = (t >= d) ? sd[t-d] : 0;
        __syncthreads();
        sd[t] += v;
        __syncthreads();
    }
    int run = bsum[blockIdx.x] + (sd[t] - s);
    #pragma unroll
    for (int j = 0; j < 4; ++j){
        int idx = base + t*4 + j;
        if (idx < NN) offs[idx] = run;
        run += loc[j];
    }
}

// atomic-free scatter: one 16B record per edge = (src, en1, en2, pad)
__global__ void k_edge_scatter(const int* __restrict__ src, const int* __restrict__ dst,
                               const float* __restrict__ ew,
                               const float2* __restrict__ dis12,
                               const int* __restrict__ offs, const int* __restrict__ slot,
                               float4* __restrict__ epk){
    int e = blockIdx.x*256 + threadIdx.x;
    if (e >= NE) return;
    int s = src[e], d = dst[e];
    int p = offs[d] + slot[e];
    float2 a = dis12[s], b = dis12[d];
    float4 v;
    v.x = __int_as_float(s);
    v.y = a.x * ew[e] * b.x;
    v.z = a.y * b.y;
    v.w = 0.f;
    epk[p] = v;
}

// agg[i,f] = selfw[i]*x[i,f] + sum_e norm[e]*x[src_e,f]  (x in bf16, acc fp32)
__global__ void k_agg(const bf16* __restrict__ xb, const float4* __restrict__ epk,
                      const int* __restrict__ offs, const int* __restrict__ cnt,
                      const float2* __restrict__ self12, int sel,
                      float* __restrict__ agg, int F){
    int i = blockIdx.x;
    int f = threadIdx.x;
    if (f >= F) return;
    float2 sw2 = self12[i];
    float sw = sel ? sw2.y : sw2.x;
    float acc = sw * b2f(xb[(size_t)i*F + f]);
    int b = offs[i];
    int e = b + cnt[i];
    int p = b;
    for (; p + 4 <= e; p += 4){
        float4 e0 = epk[p], e1 = epk[p+1], e2 = epk[p+2], e3 = epk[p+3];
        int s0 = __float_as_int(e0.x), s1 = __float_as_int(e1.x);
        int s2 = __float_as_int(e2.x), s3 = __float_as_int(e3.x);
        float n0 = sel ? e0.z : e0.y;
        float n1 = sel ? e1.z : e1.y;
        float n2 = sel ? e2.z : e2.y;
        float n3 = sel ? e3.z : e3.y;
        float v0 = b2f(xb[(size_t)s0*F + f]);
        float v1 = b2f(xb[(size_t)s1*F + f]);
        float v2 = b2f(xb[(size_t)s2*F + f]);
        float v3 = b2f(xb[(size_t)s3*F + f]);
        acc += n0*v0; acc += n1*v1; acc += n2*v2; acc += n3*v3;
    }
    for (; p < e; ++p){
        float4 e0 = epk[p];
        int s0 = __float_as_int(e0.x);
        float n0 = sel ? e0.z : e0.y;
        acc += n0 * b2f(xb[(size_t)s0*F + f]);
    }
    agg[(size_t)i*F + f] = acc;
}

// 8 nodes per block; W row loaded once, used for 8 nodes.
__global__ void k_gemm_node8(const float* __restrict__ x, const float* __restrict__ W,
                             const float* __restrict__ bias, float* __restrict__ out,
                             int F, int OF){
    extern __shared__ float xs[];   // 8*F floats
    int i0 = blockIdx.x * 8;
    int t = threadIdx.x;
    for (int idx = t; idx < 8*F; idx += blockDim.x){
        int r = idx / F, f = idx - r*F;
        xs[r*F + f] = x[(i0 + r)*F + f];
    }
    __syncthreads();
    if (t >= OF) return;
    float bj = bias[t];
    float acc0=bj, acc1=bj, acc2=bj, acc3=bj, acc4=bj, acc5=bj, acc6=bj, acc7=bj;
    for (int f = 0; f < F; ++f){
        float w = W[f*OF + t];
        acc0 += xs[0*F+f]*w; acc1 += xs[1*F+f]*w;
        acc2 += xs[2*F+f]*w; acc3 += xs[3*F+f]*w;
        acc4 += xs[4*F+f]*w; acc5 += xs[5*F+f]*w;
        acc6 += xs[6*F+f]*w; acc7 += xs[7*F+f]*w;
    }
    out[(i0+0)*OF + t] = acc0; out[(i0+1)*OF + t] = acc1;
    out[(i0+2)*OF + t] = acc2; out[(i0+3)*OF + t] = acc3;
    out[(i0+4)*OF + t] = acc4; out[(i0+5)*OF + t] = acc5;
    out[(i0+6)*OF + t] = acc6; out[(i0+7)*OF + t] = acc7;
}

__global__ void k_bn_stats(const float* __restrict__ t, float* __restrict__ sums, int OF){
    int f = threadIdx.x;
    if (f >= OF) return;
    float s = 0.f, ss = 0.f;
    for (int i = blockIdx.x; i < NN; i += gridDim.x){
        float v = t[i*OF + f];
        s += v; ss += v*v;
    }
    atomicAdd(&sums[f], s);
    atomicAdd(&sums[OF + f], ss);
}

__global__ void k_bn_finalize(const float* __restrict__ sums, const float* __restrict__ g,
                              const float* __restrict__ b, float* scale, float* shift, int OF){
    int f = threadIdx.x;
    if (f >= OF) return;
    float m = sums[f] / (float)NN;
    float v = sums[OF + f] / (float)NN - m*m;
    float sc = g[f] * rsqrtf(v + 1e-5f);
    scale[f] = sc;
    shift[f] = b[f] - m*sc;
}

__global__ void k_bn_apply(const float* __restrict__ t, const float* __restrict__ scale,
                           const float* __restrict__ shift, bf16* __restrict__ xo, int OF){
    int i = blockIdx.x, f = threadIdx.x;
    if (f >= OF) return;
    float v = t[i*OF + f] * scale[f] + shift[f];
    xo[(size_t)i*OF + f] = __float2bfloat16(v > 0.f ? v : 0.f);
}

__global__ void k_cast(const float* __restrict__ x, bf16* __restrict__ xb){
    int i = blockIdx.x*256 + threadIdx.x;
    if (i < NN*33) xb[i] = __float2bfloat16(x[i]);
}

// ---- pooling via sorted pro_batch ----
__global__ void k_gbounds(const int* __restrict__ batch, int* __restrict__ gstart){
    int i = blockIdx.x*256 + threadIdx.x;
    if (i >= NN) return;
    int pb = batch[i];
    int prev = (i == 0) ? -1 : batch[i-1];
    for (int g = prev + 1; g <= pb; ++g) gstart[g] = i;
    if (i == NN - 1){
        for (int g = pb + 1; g <= NG; ++g) gstart[g] = NN;
    }
}

__global__ void k_poolg(const bf16* __restrict__ x, const int* __restrict__ gstart,
                        float* __restrict__ pooled){
    int g = blockIdx.x, f = threadIdx.x;
    if (f >= 132) return;
    int i0 = gstart[g], i1 = gstart[g+1];
    float s = 0.f;
    for (int i = i0; i < i1; ++i) s += b2f(x[(size_t)i*132 + f]);
    float inv = 1.0f / fmaxf((float)(i1 - i0), 1.0f);
    pooled[g*132 + f] = s * inv;
}

__global__ void k_fcg1(const float* __restrict__ pooled,
                       const float* __restrict__ W, const float* __restrict__ bias,
                       float* __restrict__ h){
    __shared__ float pr[132];
    int g = blockIdx.x, t = threadIdx.x;
    if (t < 132) pr[t] = pooled[g*132 + t];
    __syncthreads();
    for (int j = t; j < 1024; j += blockDim.x){
        float acc = bias[j];
        #pragma unroll 4
        for (int f = 0; f < 132; ++f) acc += pr[f] * W[f*1024 + j];
        h[g*1024 + j] = acc > 0.f ? acc : 0.f;
    }
}

__global__ void k_fcg2(const float* __restrict__ h, const float* __restrict__ W,
                       const float* __restrict__ bias, float* __restrict__ out){
    __shared__ float hr[1024];
    int g = blockIdx.x, t = threadIdx.x;   // block 128
    for (int k = t; k < 1024; k += 128) hr[k] = h[g*1024 + k];
    __syncthreads();
    float acc = bias[t];
    #pragma unroll 4
    for (int k = 0; k < 1024; ++k) acc += hr[k] * W[k*128 + t];
    out[g*128 + t] = acc;
}

// ---------------- RNA branch ----------------
#define CH 12   // ceil(S/256) for both S=3000 and 2998

__global__ void k_tok_count(const int* __restrict__ tok, int* tcnt, int S, int V){
    __shared__ int lh[VL];
    int b = blockIdx.x / CH, c0 = (blockIdx.x % CH)*256;
    int t = threadIdx.x;
    if (t < V) lh[t] = 0;
    __syncthreads();
    int i = c0 + t;
    if (i < S) atomicAdd(&lh[tok[b*S + i]], 1);
    __syncthreads();
    if (t < V && lh[t] > 0) atomicAdd(&tcnt[b*V + t], lh[t]);
}

__global__ void k_tok_off(const int* __restrict__ tcnt, int* toff, int V){
    int b = blockIdx.x;
    if (threadIdx.x != 0) return;
    int run = 0;
    for (int v = 0; v < V; ++v){ toff[b*V + v] = run; run += tcnt[b*V + v]; }
}

__global__ void k_tok_scatter(const int* __restrict__ tok, const int* __restrict__ toff,
                              int* tcur, int* __restrict__ bucket, int S, int V){
    __shared__ int lh[VL], lbase[VL], lcur[VL];
    int b = blockIdx.x / CH, c0 = (blockIdx.x % CH)*256;
    int t = threadIdx.x;
    if (t < V){ lh[t] = 0; lcur[t] = 0; }
    __syncthreads();
    int i = c0 + t;
    int v = -1;
    if (i < S){ v = tok[b*S + i]; atomicAdd(&lh[v], 1); }
    __syncthreads();
    if (t < V && lh[t] > 0) lbase[t] = atomicAdd(&tcur[b*V + t], lh[t]);
    __syncthreads();
    if (i < S){
        int p = lbase[v] + atomicAdd(&lcur[v], 1);
        bucket[b*S + toff[b*V + v] + p] = i;
    }
}

// Wr[c*256 + o*8 + k] = bf16(W[(o*S + c)*8 + k])
__global__ void k_transposeW(const float* __restrict__ W, bf16* __restrict__ Wr, int S){
    int c = blockIdx.x, t = threadIdx.x;
    Wr[c*256 + t] = __float2bfloat16(W[((t >> 3)*S + c)*8 + (t & 7)]);
}

// A[b*256V + (o*8+k)*V + v] = sum_{c in bucket(b,v)} Wr[c*256 + o*8+k]
__global__ void k_buildA(const bf16* __restrict__ Wr, const int* __restrict__ bucket,
                         const int* __restrict__ toff, const int* __restrict__ tcnt,
                         float* __restrict__ A, int S, int V){
    int bv = blockIdx.x;
    int b = bv / V, v = bv - b*V;
    int t = threadIdx.x;            // t = o*8+k
    const int* bk = bucket + b*S + toff[b*V + v];
    int m = tcnt[b*V + v];
    float acc = 0.f;
    int idx = 0;
    for (; idx + 4 <= m; idx += 4){
        int c0 = bk[idx], c1 = bk[idx+1], c2 = bk[idx+2], c3 = bk[idx+3];
        acc += b2f(Wr[c0*256 + t]);
        acc += b2f(Wr[c1*256 + t]);
        acc += b2f(Wr[c2*256 + t]);
        acc += b2f(Wr[c3*256 + t]);
    }
    for (; idx < m; ++idx) acc += b2f(Wr[bk[idx]*256 + t]);
    A[b*(256*V) + t*V + v] = acc;
}

// G[(o*M + m)*128 + j] = sum_l emb[v,l+k] * fcxrW[(o*121+l)*128 + j],  m=k*V+v
__global__ void k_buildG(const float* __restrict__ emb, const float* __restrict__ W,
                         bf16* __restrict__ G, int V, int MT4){
    __shared__ float rows[4][128];
    int o = blockIdx.x / MT4, mt = blockIdx.x % MT4;
    int t = threadIdx.x;   // 128, j
    int kk[4];
    #pragma unroll
    for (int mm = 0; mm < 4; ++mm){
        int m = mt*4 + mm;
        int k = m / V, v = m - k*V;
        kk[mm] = k;
        rows[mm][t] = emb[v*128 + t];
    }
    __syncthreads();
    float a0 = 0.f, a1 = 0.f, a2 = 0.f, a3 = 0.f;
    const float* Wo = W + o*121*128 + t;
    for (int l = 0; l < 121; ++l){
        float w = Wo[l*128];
        a0 += rows[0][l + kk[0]] * w;
        a1 += rows[1][l + kk[1]] * w;
        a2 += rows[2][l + kk[2]] * w;
        a3 += rows[3][l + kk[3]] * w;
    }
    int M = 8*V;
    int base = (o*M + mt*4)*128 + t;
    G[base      ] = __float2bfloat16(a0);
    G[base + 128] = __float2bfloat16(a1);
    G[base + 256] = __float2bfloat16(a2);
    G[base + 384] = __float2bfloat16(a3);
}

__global__ void k_bias0_init(const float* __restrict__ fcxrb, float* __restrict__ bias0){
    bias0[threadIdx.x] = fcxrb[threadIdx.x];
}

__global__ void k_bias0_acc(const float* __restrict__ W, const float* __restrict__ cb1,
                            const float* __restrict__ cb2, float* __restrict__ bias0){
    int o = blockIdx.x, j = threadIdx.x;
    float s = 0.f;
    const float* Wo = W + o*121*128 + j;
    for (int l = 0; l < 121; ++l) s += Wo[l*128];
    atomicAdd(&bias0[j], 0.5f * (cb1[o] + cb2[o]) * s);
}

__global__ void k_init_out0(const float* __restrict__ bias0, float* __restrict__ out0){
    out0[blockIdx.x*128 + threadIdx.x] = bias0[threadIdx.x];
}

// out0[b,j] += 0.5 * sum_k X[b,k]*G[k,j]   (split-K, 8 b-rows per block)
__global__ void k_gemmR(const float* __restrict__ X, const bf16* __restrict__ G,
                        float* __restrict__ out0, int K){
    __shared__ float xs[8][256];
    int b0 = blockIdx.x * 8;
    int k0 = blockIdx.y * 256;
    int t = threadIdx.x;   // 128, j
    #pragma unroll
    for (int r = 0; r < 8; ++r){
        xs[r][t]       = X[(b0+r)*K + k0 + t];
        xs[r][t + 128] = X[(b0+r)*K + k0 + t + 128];
    }
    __syncthreads();
    float a0=0,a1=0,a2=0,a3=0,a4=0,a5=0,a6=0,a7=0;
    const bf16* Gp = G + (size_t)k0*128 + t;
    for (int kk = 0; kk < 256; ++kk){
        float g = b2f(Gp[kk*128]);
        a0 += xs[0][kk]*g; a1 += xs[1][kk]*g;
        a2 += xs[2][kk]*g; a3 += xs[3][kk]*g;
        a4 += xs[4][kk]*g; a5 += xs[5][kk]*g;
        a6 += xs[6][kk]*g; a7 += xs[7][kk]*g;
    }
    atomicAdd(&out0[(b0+0)*128 + t], 0.5f*a0);
    atomicAdd(&out0[(b0+1)*128 + t], 0.5f*a1);
    atomicAdd(&out0[(b0+2)*128 + t], 0.5f*a2);
    atomicAdd(&out0[(b0+3)*128 + t], 0.5f*a3);
    atomicAdd(&out0[(b0+4)*128 + t], 0.5f*a4);
    atomicAdd(&out0[(b0+5)*128 + t], 0.5f*a5);
    atomicAdd(&out0[(b0+6)*128 + t], 0.5f*a6);
    atomicAdd(&out0[(b0+7)*128 + t], 0.5f*a7);
}

extern "C" void kernel_launch(void* const* d_in, const int* in_sizes, int n_in,
                              void* d_out, int out_size, void* d_ws, size_t ws_size,
                              hipStream_t stream)
{
    (void)in_sizes; (void)n_in; (void)out_size; (void)ws_size;

    const float* pro_x  = (const float*)d_in[0];
    const int*   eidx   = (const int*)  d_in[1];
    const float* ew     = (const float*)d_in[2];
    const int*   pbatch = (const int*)  d_in[3];
    const int*   rna_g  = (const int*)  d_in[4];
    const int*   rna_l  = (const int*)  d_in[5];
    const float* emb1   = (const float*)d_in[6];
    const float* emb2   = (const float*)d_in[7];
    const float* convW1 = (const float*)d_in[8];
    const float* convb1 = (const float*)d_in[9];
    const float* convW2 = (const float*)d_in[10];
    const float* convb2 = (const float*)d_in[11];
    const float* fcxrW  = (const float*)d_in[12];
    const float* fcxrb  = (const float*)d_in[13];
    const float* g1W = (const float*)d_in[14];
    const float* g1b = (const float*)d_in[15];
    const float* g2W = (const float*)d_in[16];
    const float* g2b = (const float*)d_in[17];
    const float* g3W = (const float*)d_in[18];
    const float* g3b = (const float*)d_in[19];
    const float* bn1g = (const float*)d_in[20];
    const float* bn1b = (const float*)d_in[21];
    const float* bn2g = (const float*)d_in[22];
    const float* bn2b = (const float*)d_in[23];
    const float* bn3g = (const float*)d_in[24];
    const float* bn3b = (const float*)d_in[25];
    const float* fcg1W = (const float*)d_in[26];
    const float* fcg1b = (const float*)d_in[27];
    const float* fcg2W = (const float*)d_in[28];
    const float* fcg2b = (const float*)d_in[29];

    const int* e_src = eidx;
    const int* e_dst = eidx + NE;

    char* base = (char*)d_ws;
    size_t off = 0;
    auto alloc = [&](size_t bytes)->char*{
        off = (off + 255) & ~(size_t)255;
        char* p = base + off; off += bytes; return p;
    };

    // ---- zero zone (single memset) ----
    double* packed  = (double*)alloc(NN*8);
    int*   tcnt_g  = (int*)  alloc(NB*VG*4);
    int*   tcur_g  = (int*)  alloc(NB*VG*4);
    int*   tcnt_l  = (int*)  alloc(NB*VL*4);
    int*   tcur_l  = (int*)  alloc(NB*VL*4);
    float* bnsum1  = (float*)alloc(2*33*4);
    float* bnsum2  = (float*)alloc(2*66*4);
    float* bnsum3  = (float*)alloc(2*132*4);
    size_t zero_bytes = (off + 255) & ~(size_t)255;

    // ---- persistent buffers ----
    int*    cnt    = (int*)   alloc(NN*4);
    float2* dis12  = (float2*)alloc(NN*8);
    float2* self12 = (float2*)alloc(NN*8);
    int*    offs   = (int*)   alloc(NN*4);
    int*    bsum   = (int*)   alloc(64*4);
    float*  bnscale= (float*) alloc(132*4);
    float*  bnshift= (float*) alloc(132*4);
    float*  h      = (float*) alloc(NG*1024*4);
    float*  pooled = (float*) alloc(NG*132*4);
    int*    gstart = (int*)   alloc((NG+1)*4);
    float4* epk    = (float4*)alloc((size_t)NE*16);
    float*  bufA   = (float*) alloc((size_t)NN*66*4);    // agg output (max F=66)
    float*  bufB   = (float*) alloc((size_t)NN*132*4);   // gemm output (max OF=132)
    bf16*   xbA    = (bf16*)  alloc((size_t)NN*132*2);   // bf16 features
    bf16*   xbB    = (bf16*)  alloc((size_t)NN*132*2);

    // slot aliases xbA: slot is consumed by k_edge_scatter, xbA first written
    // by L1 bn_apply (later in stream). xb0 aliases xbB: read at L1 agg,
    // xbB first written at L2 bn_apply.
    int*  slot = (int*)xbA;
    bf16* xb0  = (bf16*)xbB;

    float* out0 = (float*)d_out;          // xc_rna
    float* out1 = (float*)d_out + 16384;  // xp_out

    // ---- RNA-phase scratch aliased onto bufB (RNA completes before
    // L1 gemm writes bufB; same stream serializes) ----
    {
        char* rb = (char*)bufB;
        size_t ro = 0;
        auto ralloc = [&](size_t bytes)->char*{
            ro = (ro + 255) & ~(size_t)255;
            char* p = rb + ro; ro += bytes; return p;
        };
        int* toff_g   = (int*)ralloc(NB*VG*4);
        int* toff_l   = (int*)ralloc(NB*VL*4);
        int* bucket_g = (int*)ralloc((size_t)NB*SG*4);
        int* bucket_l = (int*)ralloc((size_t)NB*SL*4);
        bf16* Wr1     = (bf16*)ralloc((size_t)SG*256*2);
        bf16* Wr2     = (bf16*)ralloc((size_t)SL*256*2);
        float* Ag     = (float*)ralloc((size_t)NB*256*VG*4);
        float* Al     = (float*)ralloc((size_t)NB*256*VL*4);
        bf16* G1      = (bf16*)ralloc((size_t)32*8*VG*128*2);
        bf16* G2      = (bf16*)ralloc((size_t)32*8*VL*128*2);
        float* bias0  = (float*)ralloc(128*4);

        hipMemsetAsync(d_ws, 0, zero_bytes, stream);

        // token bucketing
        k_tok_count<<<NB*CH, 256, 0, stream>>>(rna_g, tcnt_g, SG, VG);
        k_tok_count<<<NB*CH, 256, 0, stream>>>(rna_l, tcnt_l, SL, VL);
        k_tok_off<<<NB, 64, 0, stream>>>(tcnt_g, toff_g, VG);
        k_tok_off<<<NB, 64, 0, stream>>>(tcnt_l, toff_l, VL);
        k_tok_scatter<<<NB*CH, 256, 0, stream>>>(rna_g, toff_g, tcur_g, bucket_g, SG, VG);
        k_tok_scatter<<<NB*CH, 256, 0, stream>>>(rna_l, toff_l, tcur_l, bucket_l, SL, VL);
        // conv weight transpose + bucketed A
        k_transposeW<<<SG, 256, 0, stream>>>(convW1, Wr1, SG);
        k_transposeW<<<SL, 256, 0, stream>>>(convW2, Wr2, SL);
        k_buildA<<<NB*VG, 256, 0, stream>>>(Wr1, bucket_g, toff_g, tcnt_g, Ag, SG, VG);
        k_buildA<<<NB*VL, 256, 0, stream>>>(Wr2, bucket_l, toff_l, tcnt_l, Al, SL, VL);
        // fold emb into fcxr weight
        k_buildG<<<32*(8*VG/4), 128, 0, stream>>>(emb1, fcxrW, G1, VG, 8*VG/4);
        k_buildG<<<32*(8*VL/4), 128, 0, stream>>>(emb2, fcxrW, G2, VL, 8*VL/4);
        k_bias0_init<<<1, 128, 0, stream>>>(fcxrb, bias0);
        k_bias0_acc<<<32, 128, 0, stream>>>(fcxrW, convb1, convb2, bias0);
        k_init_out0<<<NB, 128, 0, stream>>>(bias0, out0);
        // out0 = bias0 + 0.5*(Ag·G1 + Al·G2)
        k_gemmR<<<dim3(16, (8*VG*32)/256), 128, 0, stream>>>(Ag, G1, out0, 8*VG*32);
        k_gemmR<<<dim3(16, (8*VL*32)/256), 128, 0, stream>>>(Al, G2, out0, 8*VL*32);
    }

    // ---------------- graph prep ----------------
    k_edge_deg<<<(NE+255)/256, 256, 0, stream>>>(e_dst, ew, packed, slot);
    k_node_dis<<<(NN+255)/256, 256, 0, stream>>>(packed, cnt, dis12, self12);
    k_scan1<<<49, 256, 0, stream>>>(cnt, bsum);
    k_scan2<<<1, 64, 0, stream>>>(bsum, 49);
    k_scan3<<<49, 256, 0, stream>>>(cnt, bsum, offs);
    k_edge_scatter<<<(NE+255)/256, 256, 0, stream>>>(e_src, e_dst, ew, dis12,
                                                     offs, slot, epk);
    k_cast<<<(NN*33+255)/256, 256, 0, stream>>>(pro_x, xb0);

    // ---------------- GCN layer 1 (33 -> 33) ----------------
    k_agg<<<NN, 64, 0, stream>>>(xb0, epk, offs, cnt, self12, 0, bufA, 33);
    k_gemm_node8<<<NN/8, 64, 8*33*4, stream>>>(bufA, g1W, g1b, bufB, 33, 33);
    k_bn_stats<<<256, 64, 0, stream>>>(bufB, bnsum1, 33);
    k_bn_finalize<<<1, 192, 0, stream>>>(bnsum1, bn1g, bn1b, bnscale, bnshift, 33);
    k_bn_apply<<<NN, 64, 0, stream>>>(bufB, bnscale, bnshift, xbA, 33);

    // ---------------- GCN layer 2 (33 -> 66) ----------------
    k_agg<<<NN, 64, 0, stream>>>(xbA, epk, offs, cnt, self12, 1, bufA, 33);
    k_gemm_node8<<<NN/8, 128, 8*33*4, stream>>>(bufA, g2W, g2b, bufB, 33, 66);
    k_bn_stats<<<256, 128, 0, stream>>>(bufB, bnsum2, 66);
    k_bn_finalize<<<1, 192, 0, stream>>>(bnsum2, bn2g, bn2b, bnscale, bnshift, 66);
    k_bn_apply<<<NN, 128, 0, stream>>>(bufB, bnscale, bnshift, xbB, 66);

    // ---------------- GCN layer 3 (66 -> 132) ----------------
    k_agg<<<NN, 128, 0, stream>>>(xbB, epk, offs, cnt, self12, 1, bufA, 66);
    k_gemm_node8<<<NN/8, 192, 8*66*4, stream>>>(bufA, g3W, g3b, bufB, 66, 132);
    k_bn_stats<<<256, 192, 0, stream>>>(bufB, bnsum3, 132);
    k_bn_finalize<<<1, 192, 0, stream>>>(bnsum3, bn3g, bn3b, bnscale, bnshift, 132);
    k_bn_apply<<<NN, 192, 0, stream>>>(bufB, bnscale, bnshift, xbA, 132);

    // ---------------- pool + head ----------------
    k_gbounds<<<(NN+255)/256, 256, 0, stream>>>(pbatch, gstart);
    k_poolg<<<NG, 192, 0, stream>>>(xbA, gstart, pooled);
    k_fcg1<<<NG, 256, 0, stream>>>(pooled, fcg1W, fcg1b, h);
    k_fcg2<<<NG, 128, 0, stream>>>(h, fcg2W, fcg2b, out1);
}

// Round 5
// 941.923 us; speedup vs baseline: 2.9266x; 1.2226x over previous
//
#include <hip/hip_runtime.h>
#include <hip/hip_bf16.h>

typedef __hip_bfloat16 bf16;

#define NN 50000      // nodes
#define NE 1600000    // edges
#define NG 128        // graphs
#define NB 128        // rna batch
#define SG 3000       // global seq (channels)
#define SL 2998      // local seq
#define VG 5          // global vocab
#define VL 65         // local vocab

__device__ __forceinline__ float b2f(bf16 x){ return __bfloat162float(x); }

// ---------------- graph prep ----------------
// packed[d] += 2^20 + ew  (count in high bits, weighted degree in low).
// Returned old value gives this edge's slot within d's CSR segment.
__global__ void k_edge_deg(const int* __restrict__ dst, const float* __restrict__ ew,
                           double* __restrict__ packed, int* __restrict__ slot){
    int e = blockIdx.x*256 + threadIdx.x;
    if (e >= NE) return;
    double old = atomicAdd(&packed[dst[e]], 1048576.0 + (double)ew[e]);
    slot[e] = (int)(old * (1.0/1048576.0));
}

__global__ void k_node_dis(const double* __restrict__ packed, int* __restrict__ cnt,
                           float2* __restrict__ dis12, float2* __restrict__ self12){
    int i = blockIdx.x*256 + threadIdx.x;
    if (i >= NN) return;
    double p = packed[i];
    int c = (int)(p * (1.0/1048576.0));
    float w = (float)(p - (double)c * 1048576.0);
    cnt[i] = c;
    float r1 = rsqrtf(w + 1.0f);
    float r2 = rsqrtf((float)c + 1.0f);
    dis12[i] = make_float2(r1, r2);
    self12[i] = make_float2(r1*r1, r2*r2);
}

__global__ void k_scan1(const int* __restrict__ cnt, int* bsum){
    __shared__ int sd[256];
    int t = threadIdx.x;
    int base = blockIdx.x*1024;
    int s = 0;
    #pragma unroll
    for (int j = 0; j < 4; ++j){
        int idx = base + t*4 + j;
        if (idx < NN) s += cnt[idx];
    }
    sd[t] = s; __syncthreads();
    for (int d = 128; d > 0; d >>= 1){
        if (t < d) sd[t] += sd[t+d];
        __syncthreads();
    }
    if (t == 0) bsum[blockIdx.x] = sd[0];
}

__global__ void k_scan2(int* bsum, int nb){
    if (threadIdx.x == 0 && blockIdx.x == 0){
        int run = 0;
        for (int i = 0; i < nb; ++i){ int v = bsum[i]; bsum[i] = run; run += v; }
    }
}

__global__ void k_scan3(const int* __restrict__ cnt, const int* __restrict__ bsum,
                        int* __restrict__ offs){
    __shared__ int sd[256];
    int t = threadIdx.x;
    int base = blockIdx.x*1024;
    int loc[4]; int s = 0;
    #pragma unroll
    for (int j = 0; j < 4; ++j){
        int idx = base + t*4 + j;
        loc[j] = (idx < NN) ? cnt[idx] : 0;
        s += loc[j];
    }
    sd[t] = s; __syncthreads();
    for (int d = 1; d < 256; d <<= 1){
        int v = (t >= d) ? sd[t-d] : 0;
        __syncthreads();
        sd[t] += v;
        __syncthreads();
    }
    int run = bsum[blockIdx.x] + (sd[t] - s);
    #pragma unroll
    for (int j = 0; j < 4; ++j){
        int idx = base + t*4 + j;
        if (idx < NN) offs[idx] = run;
        run += loc[j];
    }
}

// atomic-free scatter: one 16B record per edge = (src, en1, en2, pad)
__global__ void k_edge_scatter(const int* __restrict__ src, const int* __restrict__ dst,
                               const float* __restrict__ ew,
                               const float2* __restrict__ dis12,
                               const int* __restrict__ offs, const int* __restrict__ slot,
                               float4* __restrict__ epk){
    int e = blockIdx.x*256 + threadIdx.x;
    if (e >= NE) return;
    int s = src[e], d = dst[e];
    int p = offs[d] + slot[e];
    float2 a = dis12[s], b = dis12[d];
    float4 v;
    v.x = __int_as_float(s);
    v.y = a.x * ew[e] * b.x;
    v.z = a.y * b.y;
    v.w = 0.f;
    epk[p] = v;
}

// agg[i,f] = selfw[i]*x[i,f] + sum_e norm[e]*x[src_e,f]  (x in bf16, acc fp32)
__global__ void k_agg(const bf16* __restrict__ xb, const float4* __restrict__ epk,
                      const int* __restrict__ offs, const int* __restrict__ cnt,
                      const float2* __restrict__ self12, int sel,
                      float* __restrict__ agg, int F){
    int i = blockIdx.x;
    int f = threadIdx.x;
    if (f >= F) return;
    float2 sw2 = self12[i];
    float sw = sel ? sw2.y : sw2.x;
    float acc = sw * b2f(xb[(size_t)i*F + f]);
    int b = offs[i];
    int e = b + cnt[i];
    int p = b;
    for (; p + 4 <= e; p += 4){
        float4 e0 = epk[p], e1 = epk[p+1], e2 = epk[p+2], e3 = epk[p+3];
        int s0 = __float_as_int(e0.x), s1 = __float_as_int(e1.x);
        int s2 = __float_as_int(e2.x), s3 = __float_as_int(e3.x);
        float n0 = sel ? e0.z : e0.y;
        float n1 = sel ? e1.z : e1.y;
        float n2 = sel ? e2.z : e2.y;
        float n3 = sel ? e3.z : e3.y;
        float v0 = b2f(xb[(size_t)s0*F + f]);
        float v1 = b2f(xb[(size_t)s1*F + f]);
        float v2 = b2f(xb[(size_t)s2*F + f]);
        float v3 = b2f(xb[(size_t)s3*F + f]);
        acc += n0*v0; acc += n1*v1; acc += n2*v2; acc += n3*v3;
    }
    for (; p < e; ++p){
        float4 e0 = epk[p];
        int s0 = __float_as_int(e0.x);
        float n0 = sel ? e0.z : e0.y;
        acc += n0 * b2f(xb[(size_t)s0*F + f]);
    }
    agg[(size_t)i*F + f] = acc;
}

// 8 nodes per block; W row loaded once, used for 8 nodes.
__global__ void k_gemm_node8(const float* __restrict__ x, const float* __restrict__ W,
                             const float* __restrict__ bias, float* __restrict__ out,
                             int F, int OF){
    extern __shared__ float xs[];   // 8*F floats
    int i0 = blockIdx.x * 8;
    int t = threadIdx.x;
    for (int idx = t; idx < 8*F; idx += blockDim.x){
        int r = idx / F, f = idx - r*F;
        xs[r*F + f] = x[(i0 + r)*F + f];
    }
    __syncthreads();
    if (t >= OF) return;
    float bj = bias[t];
    float acc0=bj, acc1=bj, acc2=bj, acc3=bj, acc4=bj, acc5=bj, acc6=bj, acc7=bj;
    for (int f = 0; f < F; ++f){
        float w = W[f*OF + t];
        acc0 += xs[0*F+f]*w; acc1 += xs[1*F+f]*w;
        acc2 += xs[2*F+f]*w; acc3 += xs[3*F+f]*w;
        acc4 += xs[4*F+f]*w; acc5 += xs[5*F+f]*w;
        acc6 += xs[6*F+f]*w; acc7 += xs[7*F+f]*w;
    }
    out[(i0+0)*OF + t] = acc0; out[(i0+1)*OF + t] = acc1;
    out[(i0+2)*OF + t] = acc2; out[(i0+3)*OF + t] = acc3;
    out[(i0+4)*OF + t] = acc4; out[(i0+5)*OF + t] = acc5;
    out[(i0+6)*OF + t] = acc6; out[(i0+7)*OF + t] = acc7;
}

__global__ void k_bn_stats(const float* __restrict__ t, float* __restrict__ sums, int OF){
    int f = threadIdx.x;
    if (f >= OF) return;
    float s = 0.f, ss = 0.f;
    for (int i = blockIdx.x; i < NN; i += gridDim.x){
        float v = t[i*OF + f];
        s += v; ss += v*v;
    }
    atomicAdd(&sums[f], s);
    atomicAdd(&sums[OF + f], ss);
}

__global__ void k_bn_finalize(const float* __restrict__ sums, const float* __restrict__ g,
                              const float* __restrict__ b, float* scale, float* shift, int OF){
    int f = threadIdx.x;
    if (f >= OF) return;
    float m = sums[f] / (float)NN;
    float v = sums[OF + f] / (float)NN - m*m;
    float sc = g[f] * rsqrtf(v + 1e-5f);
    scale[f] = sc;
    shift[f] = b[f] - m*sc;
}

__global__ void k_bn_apply(const float* __restrict__ t, const float* __restrict__ scale,
                           const float* __restrict__ shift, bf16* __restrict__ xo, int OF){
    int i = blockIdx.x, f = threadIdx.x;
    if (f >= OF) return;
    float v = t[i*OF + f] * scale[f] + shift[f];
    xo[(size_t)i*OF + f] = __float2bfloat16(v > 0.f ? v : 0.f);
}

__global__ void k_cast(const float* __restrict__ x, bf16* __restrict__ xb){
    int i = blockIdx.x*256 + threadIdx.x;
    if (i < NN*33) xb[i] = __float2bfloat16(x[i]);
}

// ---- pooling via sorted pro_batch ----
__global__ void k_gbounds(const int* __restrict__ batch, int* __restrict__ gstart){
    int i = blockIdx.x*256 + threadIdx.x;
    if (i >= NN) return;
    int pb = batch[i];
    int prev = (i == 0) ? -1 : batch[i-1];
    for (int g = prev + 1; g <= pb; ++g) gstart[g] = i;
    if (i == NN - 1){
        for (int g = pb + 1; g <= NG; ++g) gstart[g] = NN;
    }
}

// grid (NG, 4): each strip sums every 4th node of graph g, atomic into poolsum
__global__ void k_poolsum(const bf16* __restrict__ x, const int* __restrict__ gstart,
                          float* __restrict__ poolsum){
    int g = blockIdx.x, strip = blockIdx.y, f = threadIdx.x;
    if (f >= 132) return;
    int i0 = gstart[g], i1 = gstart[g+1];
    float s = 0.f;
    for (int i = i0 + strip; i < i1; i += 4) s += b2f(x[(size_t)i*132 + f]);
    atomicAdd(&poolsum[g*132 + f], s);
}

// 1024 threads: one j per thread, 16 waves hide W-load latency
__global__ void k_fcg1(const float* __restrict__ poolsum, const int* __restrict__ gstart,
                       const float* __restrict__ W, const float* __restrict__ bias,
                       float* __restrict__ h){
    __shared__ float pr[132];
    int g = blockIdx.x, t = threadIdx.x;   // 1024
    if (t < 132){
        float inv = 1.0f / fmaxf((float)(gstart[g+1] - gstart[g]), 1.0f);
        pr[t] = poolsum[g*132 + t] * inv;
    }
    __syncthreads();
    float acc = bias[t];
    #pragma unroll 4
    for (int f = 0; f < 132; ++f) acc += pr[f] * W[f*1024 + t];
    h[g*1024 + t] = acc > 0.f ? acc : 0.f;
}

// 1024 threads = 8 K-slices x 128 j; LDS reduce the 8 partials
__global__ void k_fcg2(const float* __restrict__ h, const float* __restrict__ W,
                       const float* __restrict__ bias, float* __restrict__ out){
    __shared__ float hr[1024];
    __shared__ float part[8][128];
    int g = blockIdx.x, t = threadIdx.x;   // 1024
    hr[t] = h[g*1024 + t];
    __syncthreads();
    int ks = t >> 7, j = t & 127;
    const float* Wp = W + (ks*128)*128 + j;
    const float* hp = hr + ks*128;
    float acc = 0.f;
    #pragma unroll 8
    for (int kk = 0; kk < 128; ++kk) acc += hp[kk] * Wp[(size_t)kk*128];
    part[ks][j] = acc;
    __syncthreads();
    if (t < 128){
        float s = bias[t];
        #pragma unroll
        for (int r = 0; r < 8; ++r) s += part[r][t];
        out[g*128 + t] = s;
    }
}

// ---------------- RNA branch ----------------
#define CH 12   // ceil(S/256) for both S=3000 and 2998

__global__ void k_tok_count(const int* __restrict__ tok, int* tcnt, int S, int V){
    __shared__ int lh[VL];
    int b = blockIdx.x / CH, c0 = (blockIdx.x % CH)*256;
    int t = threadIdx.x;
    if (t < V) lh[t] = 0;
    __syncthreads();
    int i = c0 + t;
    if (i < S) atomicAdd(&lh[tok[b*S + i]], 1);
    __syncthreads();
    if (t < V && lh[t] > 0) atomicAdd(&tcnt[b*V + t], lh[t]);
}

__global__ void k_tok_off(const int* __restrict__ tcnt, int* toff, int V){
    int b = blockIdx.x;
    if (threadIdx.x != 0) return;
    int run = 0;
    for (int v = 0; v < V; ++v){ toff[b*V + v] = run; run += tcnt[b*V + v]; }
}

__global__ void k_tok_scatter(const int* __restrict__ tok, const int* __restrict__ toff,
                              int* tcur, int* __restrict__ bucket, int S, int V){
    __shared__ int lh[VL], lbase[VL], lcur[VL];
    int b = blockIdx.x / CH, c0 = (blockIdx.x % CH)*256;
    int t = threadIdx.x;
    if (t < V){ lh[t] = 0; lcur[t] = 0; }
    __syncthreads();
    int i = c0 + t;
    int v = -1;
    if (i < S){ v = tok[b*S + i]; atomicAdd(&lh[v], 1); }
    __syncthreads();
    if (t < V && lh[t] > 0) lbase[t] = atomicAdd(&tcur[b*V + t], lh[t]);
    __syncthreads();
    if (i < S){
        int p = lbase[v] + atomicAdd(&lcur[v], 1);
        bucket[b*S + toff[b*V + v] + p] = i;
    }
}

// Wr[c*256 + o*8 + k] = bf16(W[(o*S + c)*8 + k])
__global__ void k_transposeW(const float* __restrict__ W, bf16* __restrict__ Wr, int S){
    int c = blockIdx.x, t = threadIdx.x;
    Wr[c*256 + t] = __float2bfloat16(W[((t >> 3)*S + c)*8 + (t & 7)]);
}

// A[b*256V + (o*8+k)*V + v] = sum_{c in bucket(b,v)} Wr[c*256 + o*8+k]
__global__ void k_buildA(const bf16* __restrict__ Wr, const int* __restrict__ bucket,
                         const int* __restrict__ toff, const int* __restrict__ tcnt,
                         float* __restrict__ A, int S, int V){
    int bv = blockIdx.x;
    int b = bv / V, v = bv - b*V;
    int t = threadIdx.x;            // t = o*8+k
    const int* bk = bucket + b*S + toff[b*V + v];
    int m = tcnt[b*V + v];
    float acc = 0.f;
    int idx = 0;
    for (; idx + 4 <= m; idx += 4){
        int c0 = bk[idx], c1 = bk[idx+1], c2 = bk[idx+2], c3 = bk[idx+3];
        acc += b2f(Wr[c0*256 + t]);
        acc += b2f(Wr[c1*256 + t]);
        acc += b2f(Wr[c2*256 + t]);
        acc += b2f(Wr[c3*256 + t]);
    }
    for (; idx < m; ++idx) acc += b2f(Wr[bk[idx]*256 + t]);
    A[b*(256*V) + t*V + v] = acc;
}

// G[(o*M + m)*128 + j] = sum_l emb[v,l+k] * fcxrW[(o*121+l)*128 + j],  m=k*V+v
__global__ void k_buildG(const float* __restrict__ emb, const float* __restrict__ W,
                         bf16* __restrict__ G, int V, int MT4){
    __shared__ float rows[4][128];
    int o = blockIdx.x / MT4, mt = blockIdx.x % MT4;
    int t = threadIdx.x;   // 128, j
    int kk[4];
    #pragma unroll
    for (int mm = 0; mm < 4; ++mm){
        int m = mt*4 + mm;
        int k = m / V, v = m - k*V;
        kk[mm] = k;
        rows[mm][t] = emb[v*128 + t];
    }
    __syncthreads();
    float a0 = 0.f, a1 = 0.f, a2 = 0.f, a3 = 0.f;
    const float* Wo = W + o*121*128 + t;
    for (int l = 0; l < 121; ++l){
        float w = Wo[l*128];
        a0 += rows[0][l + kk[0]] * w;
        a1 += rows[1][l + kk[1]] * w;
        a2 += rows[2][l + kk[2]] * w;
        a3 += rows[3][l + kk[3]] * w;
    }
    int M = 8*V;
    int base = (o*M + mt*4)*128 + t;
    G[base      ] = __float2bfloat16(a0);
    G[base + 128] = __float2bfloat16(a1);
    G[base + 256] = __float2bfloat16(a2);
    G[base + 384] = __float2bfloat16(a3);
}

__global__ void k_bias0_init(const float* __restrict__ fcxrb, float* __restrict__ bias0){
    bias0[threadIdx.x] = fcxrb[threadIdx.x];
}

__global__ void k_bias0_acc(const float* __restrict__ W, const float* __restrict__ cb1,
                            const float* __restrict__ cb2, float* __restrict__ bias0){
    int o = blockIdx.x, j = threadIdx.x;
    float s = 0.f;
    const float* Wo = W + o*121*128 + j;
    for (int l = 0; l < 121; ++l) s += Wo[l*128];
    atomicAdd(&bias0[j], 0.5f * (cb1[o] + cb2[o]) * s);
}

__global__ void k_init_out0(const float* __restrict__ bias0, float* __restrict__ out0){
    out0[blockIdx.x*128 + threadIdx.x] = bias0[threadIdx.x];
}

// out0[b,j] += 0.5 * sum_k X[b,k]*G[k,j]   (split-K, 8 b-rows per block)
__global__ void k_gemmR(const float* __restrict__ X, const bf16* __restrict__ G,
                        float* __restrict__ out0, int K){
    __shared__ float xs[8][256];
    int b0 = blockIdx.x * 8;
    int k0 = blockIdx.y * 256;
    int t = threadIdx.x;   // 128, j
    #pragma unroll
    for (int r = 0; r < 8; ++r){
        xs[r][t]       = X[(b0+r)*K + k0 + t];
        xs[r][t + 128] = X[(b0+r)*K + k0 + t + 128];
    }
    __syncthreads();
    float a0=0,a1=0,a2=0,a3=0,a4=0,a5=0,a6=0,a7=0;
    const bf16* Gp = G + (size_t)k0*128 + t;
    for (int kk = 0; kk < 256; ++kk){
        float g = b2f(Gp[kk*128]);
        a0 += xs[0][kk]*g; a1 += xs[1][kk]*g;
        a2 += xs[2][kk]*g; a3 += xs[3][kk]*g;
        a4 += xs[4][kk]*g; a5 += xs[5][kk]*g;
        a6 += xs[6][kk]*g; a7 += xs[7][kk]*g;
    }
    atomicAdd(&out0[(b0+0)*128 + t], 0.5f*a0);
    atomicAdd(&out0[(b0+1)*128 + t], 0.5f*a1);
    atomicAdd(&out0[(b0+2)*128 + t], 0.5f*a2);
    atomicAdd(&out0[(b0+3)*128 + t], 0.5f*a3);
    atomicAdd(&out0[(b0+4)*128 + t], 0.5f*a4);
    atomicAdd(&out0[(b0+5)*128 + t], 0.5f*a5);
    atomicAdd(&out0[(b0+6)*128 + t], 0.5f*a6);
    atomicAdd(&out0[(b0+7)*128 + t], 0.5f*a7);
}

extern "C" void kernel_launch(void* const* d_in, const int* in_sizes, int n_in,
                              void* d_out, int out_size, void* d_ws, size_t ws_size,
                              hipStream_t stream)
{
    (void)in_sizes; (void)n_in; (void)out_size; (void)ws_size;

    const float* pro_x  = (const float*)d_in[0];
    const int*   eidx   = (const int*)  d_in[1];
    const float* ew     = (const float*)d_in[2];
    const int*   pbatch = (const int*)  d_in[3];
    const int*   rna_g  = (const int*)  d_in[4];
    const int*   rna_l  = (const int*)  d_in[5];
    const float* emb1   = (const float*)d_in[6];
    const float* emb2   = (const float*)d_in[7];
    const float* convW1 = (const float*)d_in[8];
    const float* convb1 = (const float*)d_in[9];
    const float* convW2 = (const float*)d_in[10];
    const float* convb2 = (const float*)d_in[11];
    const float* fcxrW  = (const float*)d_in[12];
    const float* fcxrb  = (const float*)d_in[13];
    const float* g1W = (const float*)d_in[14];
    const float* g1b = (const float*)d_in[15];
    const float* g2W = (const float*)d_in[16];
    const float* g2b = (const float*)d_in[17];
    const float* g3W = (const float*)d_in[18];
    const float* g3b = (const float*)d_in[19];
    const float* bn1g = (const float*)d_in[20];
    const float* bn1b = (const float*)d_in[21];
    const float* bn2g = (const float*)d_in[22];
    const float* bn2b = (const float*)d_in[23];
    const float* bn3g = (const float*)d_in[24];
    const float* bn3b = (const float*)d_in[25];
    const float* fcg1W = (const float*)d_in[26];
    const float* fcg1b = (const float*)d_in[27];
    const float* fcg2W = (const float*)d_in[28];
    const float* fcg2b = (const float*)d_in[29];

    const int* e_src = eidx;
    const int* e_dst = eidx + NE;

    char* base = (char*)d_ws;
    size_t off = 0;
    auto alloc = [&](size_t bytes)->char*{
        off = (off + 255) & ~(size_t)255;
        char* p = base + off; off += bytes; return p;
    };

    // ---- zero zone (single memset) ----
    double* packed  = (double*)alloc(NN*8);
    int*   tcnt_g  = (int*)  alloc(NB*VG*4);
    int*   tcur_g  = (int*)  alloc(NB*VG*4);
    int*   tcnt_l  = (int*)  alloc(NB*VL*4);
    int*   tcur_l  = (int*)  alloc(NB*VL*4);
    float* bnsum1  = (float*)alloc(2*33*4);
    float* bnsum2  = (float*)alloc(2*66*4);
    float* bnsum3  = (float*)alloc(2*132*4);
    float* poolsum = (float*)alloc(NG*132*4);
    size_t zero_bytes = (off + 255) & ~(size_t)255;

    // ---- persistent buffers ----
    int*    cnt    = (int*)   alloc(NN*4);
    float2* dis12  = (float2*)alloc(NN*8);
    float2* self12 = (float2*)alloc(NN*8);
    int*    offs   = (int*)   alloc(NN*4);
    int*    bsum   = (int*)   alloc(64*4);
    float*  bnscale= (float*) alloc(132*4);
    float*  bnshift= (float*) alloc(132*4);
    float*  h      = (float*) alloc(NG*1024*4);
    int*    gstart = (int*)   alloc((NG+1)*4);
    float4* epk    = (float4*)alloc((size_t)NE*16);
    float*  bufA   = (float*) alloc((size_t)NN*66*4);    // agg output (max F=66)
    float*  bufB   = (float*) alloc((size_t)NN*132*4);   // gemm output (max OF=132)
    bf16*   xbA    = (bf16*)  alloc((size_t)NN*132*2);   // bf16 features
    bf16*   xbB    = (bf16*)  alloc((size_t)NN*132*2);

    // slot aliases xbA: slot is consumed by k_edge_scatter, xbA first written
    // by L1 bn_apply (later in stream). xb0 aliases xbB: read at L1 agg,
    // xbB first written at L2 bn_apply.
    int*  slot = (int*)xbA;
    bf16* xb0  = (bf16*)xbB;

    float* out0 = (float*)d_out;          // xc_rna
    float* out1 = (float*)d_out + 16384;  // xp_out

    // ---- RNA-phase scratch aliased onto bufB (RNA completes before
    // L1 gemm writes bufB; same stream serializes) ----
    {
        char* rb = (char*)bufB;
        size_t ro = 0;
        auto ralloc = [&](size_t bytes)->char*{
            ro = (ro + 255) & ~(size_t)255;
            char* p = rb + ro; ro += bytes; return p;
        };
        int* toff_g   = (int*)ralloc(NB*VG*4);
        int* toff_l   = (int*)ralloc(NB*VL*4);
        int* bucket_g = (int*)ralloc((size_t)NB*SG*4);
        int* bucket_l = (int*)ralloc((size_t)NB*SL*4);
        bf16* Wr1     = (bf16*)ralloc((size_t)SG*256*2);
        bf16* Wr2     = (bf16*)ralloc((size_t)SL*256*2);
        float* Ag     = (float*)ralloc((size_t)NB*256*VG*4);
        float* Al     = (float*)ralloc((size_t)NB*256*VL*4);
        bf16* G1      = (bf16*)ralloc((size_t)32*8*VG*128*2);
        bf16* G2      = (bf16*)ralloc((size_t)32*8*VL*128*2);
        float* bias0  = (float*)ralloc(128*4);

        hipMemsetAsync(d_ws, 0, zero_bytes, stream);

        // token bucketing
        k_tok_count<<<NB*CH, 256, 0, stream>>>(rna_g, tcnt_g, SG, VG);
        k_tok_count<<<NB*CH, 256, 0, stream>>>(rna_l, tcnt_l, SL, VL);
        k_tok_off<<<NB, 64, 0, stream>>>(tcnt_g, toff_g, VG);
        k_tok_off<<<NB, 64, 0, stream>>>(tcnt_l, toff_l, VL);
        k_tok_scatter<<<NB*CH, 256, 0, stream>>>(rna_g, toff_g, tcur_g, bucket_g, SG, VG);
        k_tok_scatter<<<NB*CH, 256, 0, stream>>>(rna_l, toff_l, tcur_l, bucket_l, SL, VL);
        // conv weight transpose + bucketed A
        k_transposeW<<<SG, 256, 0, stream>>>(convW1, Wr1, SG);
        k_transposeW<<<SL, 256, 0, stream>>>(convW2, Wr2, SL);
        k_buildA<<<NB*VG, 256, 0, stream>>>(Wr1, bucket_g, toff_g, tcnt_g, Ag, SG, VG);
        k_buildA<<<NB*VL, 256, 0, stream>>>(Wr2, bucket_l, toff_l, tcnt_l, Al, SL, VL);
        // fold emb into fcxr weight
        k_buildG<<<32*(8*VG/4), 128, 0, stream>>>(emb1, fcxrW, G1, VG, 8*VG/4);
        k_buildG<<<32*(8*VL/4), 128, 0, stream>>>(emb2, fcxrW, G2, VL, 8*VL/4);
        k_bias0_init<<<1, 128, 0, stream>>>(fcxrb, bias0);
        k_bias0_acc<<<32, 128, 0, stream>>>(fcxrW, convb1, convb2, bias0);
        k_init_out0<<<NB, 128, 0, stream>>>(bias0, out0);
        // out0 = bias0 + 0.5*(Ag·G1 + Al·G2)
        k_gemmR<<<dim3(16, (8*VG*32)/256), 128, 0, stream>>>(Ag, G1, out0, 8*VG*32);
        k_gemmR<<<dim3(16, (8*VL*32)/256), 128, 0, stream>>>(Al, G2, out0, 8*VL*32);
    }

    // ---------------- graph prep ----------------
    k_edge_deg<<<(NE+255)/256, 256, 0, stream>>>(e_dst, ew, packed, slot);
    k_node_dis<<<(NN+255)/256, 256, 0, stream>>>(packed, cnt, dis12, self12);
    k_scan1<<<49, 256, 0, stream>>>(cnt, bsum);
    k_scan2<<<1, 64, 0, stream>>>(bsum, 49);
    k_scan3<<<49, 256, 0, stream>>>(cnt, bsum, offs);
    k_edge_scatter<<<(NE+255)/256, 256, 0, stream>>>(e_src, e_dst, ew, dis12,
                                                     offs, slot, epk);
    k_cast<<<(NN*33+255)/256, 256, 0, stream>>>(pro_x, xb0);

    // ---------------- GCN layer 1 (33 -> 33) ----------------
    k_agg<<<NN, 64, 0, stream>>>(xb0, epk, offs, cnt, self12, 0, bufA, 33);
    k_gemm_node8<<<NN/8, 64, 8*33*4, stream>>>(bufA, g1W, g1b, bufB, 33, 33);
    k_bn_stats<<<256, 64, 0, stream>>>(bufB, bnsum1, 33);
    k_bn_finalize<<<1, 192, 0, stream>>>(bnsum1, bn1g, bn1b, bnscale, bnshift, 33);
    k_bn_apply<<<NN, 64, 0, stream>>>(bufB, bnscale, bnshift, xbA, 33);

    // ---------------- GCN layer 2 (33 -> 66) ----------------
    k_agg<<<NN, 64, 0, stream>>>(xbA, epk, offs, cnt, self12, 1, bufA, 33);
    k_gemm_node8<<<NN/8, 128, 8*33*4, stream>>>(bufA, g2W, g2b, bufB, 33, 66);
    k_bn_stats<<<256, 128, 0, stream>>>(bufB, bnsum2, 66);
    k_bn_finalize<<<1, 192, 0, stream>>>(bnsum2, bn2g, bn2b, bnscale, bnshift, 66);
    k_bn_apply<<<NN, 128, 0, stream>>>(bufB, bnscale, bnshift, xbB, 66);

    // ---------------- GCN layer 3 (66 -> 132) ----------------
    k_agg<<<NN, 128, 0, stream>>>(xbB, epk, offs, cnt, self12, 1, bufA, 66);
    k_gemm_node8<<<NN/8, 192, 8*66*4, stream>>>(bufA, g3W, g3b, bufB, 66, 132);
    k_bn_stats<<<256, 192, 0, stream>>>(bufB, bnsum3, 132);
    k_bn_finalize<<<1, 192, 0, stream>>>(bnsum3, bn3g, bn3b, bnscale, bnshift, 132);
    k_bn_apply<<<NN, 192, 0, stream>>>(bufB, bnscale, bnshift, xbA, 132);

    // ---------------- pool + head ----------------
    k_gbounds<<<(NN+255)/256, 256, 0, stream>>>(pbatch, gstart);
    k_poolsum<<<dim3(NG,4), 192, 0, stream>>>(xbA, gstart, poolsum);
    k_fcg1<<<NG, 1024, 0, stream>>>(poolsum, gstart, fcg1W, fcg1b, h);
    k_fcg2<<<NG, 1024, 0, stream>>>(h, fcg2W, fcg2b, out1);
}

// Round 6
// 910.871 us; speedup vs baseline: 3.0264x; 1.0341x over previous
//
#include <hip/hip_runtime.h>
#include <hip/hip_bf16.h>

typedef __hip_bfloat16 bf16;

#define NN 50000      // nodes
#define NE 1600000    // edges
#define NG 128        // graphs
#define NB 128        // rna batch
#define SG 3000       // global seq (channels)
#define SL 2998       // local seq
#define VG 5          // global vocab
#define VL 65         // local vocab

__device__ __forceinline__ float b2f(bf16 x){ return __bfloat162float(x); }
__device__ __forceinline__ float blo(unsigned u){ return __uint_as_float(u << 16); }
__device__ __forceinline__ float bhi(unsigned u){ return __uint_as_float(u & 0xffff0000u); }

// ---------------- graph prep ----------------
// packed[d] += 2^20 + ew  (count in high bits, weighted degree low).
// HW f64 atomic (unsafeAtomicAdd) returns old value -> this edge's CSR slot.
__global__ void k_edge_deg(const int* __restrict__ dst, const float* __restrict__ ew,
                           double* __restrict__ packed, int* __restrict__ slot){
    int e = blockIdx.x*256 + threadIdx.x;
    if (e >= NE) return;
    double old = unsafeAtomicAdd(&packed[dst[e]], 1048576.0 + (double)ew[e]);
    slot[e] = (int)(old * (1.0/1048576.0));
}

__global__ void k_node_dis(const double* __restrict__ packed, int* __restrict__ cnt,
                           float2* __restrict__ dis12, float2* __restrict__ self12){
    int i = blockIdx.x*256 + threadIdx.x;
    if (i >= NN) return;
    double p = packed[i];
    int c = (int)(p * (1.0/1048576.0));
    float w = (float)(p - (double)c * 1048576.0);
    cnt[i] = c;
    float r1 = rsqrtf(w + 1.0f);
    float r2 = rsqrtf((float)c + 1.0f);
    dis12[i] = make_float2(r1, r2);
    self12[i] = make_float2(r1*r1, r2*r2);
}

__global__ void k_scan1(const int* __restrict__ cnt, int* bsum){
    __shared__ int sd[256];
    int t = threadIdx.x;
    int base = blockIdx.x*1024;
    int s = 0;
    #pragma unroll
    for (int j = 0; j < 4; ++j){
        int idx = base + t*4 + j;
        if (idx < NN) s += cnt[idx];
    }
    sd[t] = s; __syncthreads();
    for (int d = 128; d > 0; d >>= 1){
        if (t < d) sd[t] += sd[t+d];
        __syncthreads();
    }
    if (t == 0) bsum[blockIdx.x] = sd[0];
}

__global__ void k_scan2(int* bsum, int nb){
    if (threadIdx.x == 0 && blockIdx.x == 0){
        int run = 0;
        for (int i = 0; i < nb; ++i){ int v = bsum[i]; bsum[i] = run; run += v; }
    }
}

__global__ void k_scan3(const int* __restrict__ cnt, const int* __restrict__ bsum,
                        int* __restrict__ offs){
    __shared__ int sd[256];
    int t = threadIdx.x;
    int base = blockIdx.x*1024;
    int loc[4]; int s = 0;
    #pragma unroll
    for (int j = 0; j < 4; ++j){
        int idx = base + t*4 + j;
        loc[j] = (idx < NN) ? cnt[idx] : 0;
        s += loc[j];
    }
    sd[t] = s; __syncthreads();
    for (int d = 1; d < 256; d <<= 1){
        int v = (t >= d) ? sd[t-d] : 0;
        __syncthreads();
        sd[t] += v;
        __syncthreads();
    }
    int run = bsum[blockIdx.x] + (sd[t] - s);
    #pragma unroll
    for (int j = 0; j < 4; ++j){
        int idx = base + t*4 + j;
        if (idx < NN) offs[idx] = run;
        run += loc[j];
    }
}

// atomic-free scatter: one 16B record per edge = (src, en1, en2, pad)
__global__ void k_edge_scatter(const int* __restrict__ src, const int* __restrict__ dst,
                               const float* __restrict__ ew,
                               const float2* __restrict__ dis12,
                               const int* __restrict__ offs, const int* __restrict__ slot,
                               float4* __restrict__ epk){
    int e = blockIdx.x*256 + threadIdx.x;
    if (e >= NE) return;
    int s = src[e], d = dst[e];
    int p = offs[d] + slot[e];
    float2 a = dis12[s], b = dis12[d];
    float4 v;
    v.x = __int_as_float(s);
    v.y = a.x * ew[e] * b.x;
    v.z = a.y * b.y;
    v.w = 0.f;
    epk[p] = v;
}

// agg[i,:] = selfw[i]*x[i,:] + sum_e norm[e]*x[src_e,:]
// QF = uint2s per padded row (Fs = 4*QF), GRP edge-groups per wave.
// 4 nodes per 256-thread block (one wave per node).
template<int QF, int GRP>
__global__ void k_aggT(const bf16* __restrict__ xb, const float4* __restrict__ epk,
                       const int* __restrict__ offs, const int* __restrict__ cnt,
                       const float2* __restrict__ self12, int sel,
                       float* __restrict__ agg){
    const int LPG = 64 / GRP;
    const int Fs  = 4 * QF;
    int node = blockIdx.x*4 + (threadIdx.x >> 6);
    if (node >= NN) return;
    int lane = threadIdx.x & 63;
    int grp  = lane / LPG;
    int gl   = lane % LPG;
    bool act = gl < QF;
    const uint2* xw = (const uint2*)xb;
    float a0=0.f, a1=0.f, a2=0.f, a3=0.f;
    int b = offs[node], e = b + cnt[node];
    if (act){
        if (grp == 0){
            float2 sw2 = self12[node];
            float sw = sel ? sw2.y : sw2.x;
            uint2 u = xw[(size_t)node*QF + gl];
            a0 = sw*blo(u.x); a1 = sw*bhi(u.x); a2 = sw*blo(u.y); a3 = sw*bhi(u.y);
        }
        int p = b + grp;
        for (; p + GRP < e; p += 2*GRP){
            float4 e0 = epk[p];
            float4 e1 = epk[p + GRP];
            int s0 = __float_as_int(e0.x); float n0 = sel ? e0.z : e0.y;
            int s1 = __float_as_int(e1.x); float n1 = sel ? e1.z : e1.y;
            uint2 u0 = xw[(size_t)s0*QF + gl];
            uint2 u1 = xw[(size_t)s1*QF + gl];
            a0 += n0*blo(u0.x); a1 += n0*bhi(u0.x); a2 += n0*blo(u0.y); a3 += n0*bhi(u0.y);
            a0 += n1*blo(u1.x); a1 += n1*bhi(u1.x); a2 += n1*blo(u1.y); a3 += n1*bhi(u1.y);
        }
        if (p < e){
            float4 e0 = epk[p];
            int s0 = __float_as_int(e0.x); float n0 = sel ? e0.z : e0.y;
            uint2 u0 = xw[(size_t)s0*QF + gl];
            a0 += n0*blo(u0.x); a1 += n0*bhi(u0.x); a2 += n0*blo(u0.y); a3 += n0*bhi(u0.y);
        }
    }
    #pragma unroll
    for (int m = LPG; m < 64; m <<= 1){
        a0 += __shfl_xor(a0, m);
        a1 += __shfl_xor(a1, m);
        a2 += __shfl_xor(a2, m);
        a3 += __shfl_xor(a3, m);
    }
    if (act && grp == 0){
        ((float4*)(agg + (size_t)node*Fs))[gl] = make_float4(a0, a1, a2, a3);
    }
}

// 8 nodes per block; W row loaded once, used for 8 nodes. Fs = padded x stride.
__global__ void k_gemm_node8(const float* __restrict__ x, const float* __restrict__ W,
                             const float* __restrict__ bias, float* __restrict__ out,
                             int F, int Fs, int OF){
    extern __shared__ float xs[];   // 8*Fs floats
    int i0 = blockIdx.x * 8;
    int t = threadIdx.x;
    for (int idx = t; idx < 8*Fs; idx += blockDim.x){
        int r = idx / Fs, f = idx - r*Fs;
        xs[r*Fs + f] = x[(size_t)(i0 + r)*Fs + f];
    }
    __syncthreads();
    if (t >= OF) return;
    float bj = bias[t];
    float acc0=bj, acc1=bj, acc2=bj, acc3=bj, acc4=bj, acc5=bj, acc6=bj, acc7=bj;
    for (int f = 0; f < F; ++f){
        float w = W[f*OF + t];
        acc0 += xs[0*Fs+f]*w; acc1 += xs[1*Fs+f]*w;
        acc2 += xs[2*Fs+f]*w; acc3 += xs[3*Fs+f]*w;
        acc4 += xs[4*Fs+f]*w; acc5 += xs[5*Fs+f]*w;
        acc6 += xs[6*Fs+f]*w; acc7 += xs[7*Fs+f]*w;
    }
    out[(i0+0)*OF + t] = acc0; out[(i0+1)*OF + t] = acc1;
    out[(i0+2)*OF + t] = acc2; out[(i0+3)*OF + t] = acc3;
    out[(i0+4)*OF + t] = acc4; out[(i0+5)*OF + t] = acc5;
    out[(i0+6)*OF + t] = acc6; out[(i0+7)*OF + t] = acc7;
}

__global__ void k_bn_stats(const float* __restrict__ t, float* __restrict__ sums, int OF){
    int f = threadIdx.x;
    if (f >= OF) return;
    float s = 0.f, ss = 0.f;
    for (int i = blockIdx.x; i < NN; i += gridDim.x){
        float v = t[(size_t)i*OF + f];
        s += v; ss += v*v;
    }
    unsafeAtomicAdd(&sums[f], s);
    unsafeAtomicAdd(&sums[OF + f], ss);
}

__global__ void k_bn_finalize(const float* __restrict__ sums, const float* __restrict__ g,
                              const float* __restrict__ b, float* scale, float* shift, int OF){
    int f = threadIdx.x;
    if (f >= OF) return;
    float m = sums[f] / (float)NN;
    float v = sums[OF + f] / (float)NN - m*m;
    float sc = g[f] * rsqrtf(v + 1e-5f);
    scale[f] = sc;
    shift[f] = b[f] - m*sc;
}

// writes padded bf16 rows (stride OS, zeros in [OF, OS))
__global__ void k_bn_apply(const float* __restrict__ t, const float* __restrict__ scale,
                           const float* __restrict__ shift, bf16* __restrict__ xo,
                           int OF, int OS){
    int i = blockIdx.x, f = threadIdx.x;
    if (f >= OS) return;
    float v = 0.f;
    if (f < OF){
        v = t[(size_t)i*OF + f] * scale[f] + shift[f];
        v = v > 0.f ? v : 0.f;
    }
    xo[(size_t)i*OS + f] = __float2bfloat16(v);
}

// pro_x [NN,33] -> padded bf16 [NN,36]
__global__ void k_cast(const float* __restrict__ x, bf16* __restrict__ xb){
    int i = blockIdx.x*256 + threadIdx.x;
    if (i >= NN*36) return;
    int n = i / 36, f = i - n*36;
    float v = (f < 33) ? x[n*33 + f] : 0.f;
    xb[i] = __float2bfloat16(v);
}

// ---- pooling via sorted pro_batch ----
__global__ void k_gbounds(const int* __restrict__ batch, int* __restrict__ gstart){
    int i = blockIdx.x*256 + threadIdx.x;
    if (i >= NN) return;
    int pb = batch[i];
    int prev = (i == 0) ? -1 : batch[i-1];
    for (int g = prev + 1; g <= pb; ++g) gstart[g] = i;
    if (i == NN - 1){
        for (int g = pb + 1; g <= NG; ++g) gstart[g] = NN;
    }
}

// grid (NG, 4): each strip sums every 4th node of graph g, atomic into poolsum
__global__ void k_poolsum(const bf16* __restrict__ x, const int* __restrict__ gstart,
                          float* __restrict__ poolsum){
    int g = blockIdx.x, strip = blockIdx.y, f = threadIdx.x;
    if (f >= 132) return;
    int i0 = gstart[g], i1 = gstart[g+1];
    float s = 0.f;
    for (int i = i0 + strip; i < i1; i += 4) s += b2f(x[(size_t)i*132 + f]);
    unsafeAtomicAdd(&poolsum[g*132 + f], s);
}

// 1024 threads: one j per thread, 16 waves hide W-load latency
__global__ void k_fcg1(const float* __restrict__ poolsum, const int* __restrict__ gstart,
                       const float* __restrict__ W, const float* __restrict__ bias,
                       float* __restrict__ h){
    __shared__ float pr[132];
    int g = blockIdx.x, t = threadIdx.x;   // 1024
    if (t < 132){
        float inv = 1.0f / fmaxf((float)(gstart[g+1] - gstart[g]), 1.0f);
        pr[t] = poolsum[g*132 + t] * inv;
    }
    __syncthreads();
    float acc = bias[t];
    #pragma unroll 4
    for (int f = 0; f < 132; ++f) acc += pr[f] * W[f*1024 + t];
    h[g*1024 + t] = acc > 0.f ? acc : 0.f;
}

// 1024 threads = 8 K-slices x 128 j; LDS reduce the 8 partials
__global__ void k_fcg2(const float* __restrict__ h, const float* __restrict__ W,
                       const float* __restrict__ bias, float* __restrict__ out){
    __shared__ float hr[1024];
    __shared__ float part[8][128];
    int g = blockIdx.x, t = threadIdx.x;   // 1024
    hr[t] = h[g*1024 + t];
    __syncthreads();
    int ks = t >> 7, j = t & 127;
    const float* Wp = W + (ks*128)*128 + j;
    const float* hp = hr + ks*128;
    float acc = 0.f;
    #pragma unroll 8
    for (int kk = 0; kk < 128; ++kk) acc += hp[kk] * Wp[(size_t)kk*128];
    part[ks][j] = acc;
    __syncthreads();
    if (t < 128){
        float s = bias[t];
        #pragma unroll
        for (int r = 0; r < 8; ++r) s += part[r][t];
        out[g*128 + t] = s;
    }
}

// ---------------- RNA branch ----------------
#define CH 12   // ceil(S/256) for both S=3000 and 2998

__global__ void k_tok_count(const int* __restrict__ tok, int* tcnt, int S, int V){
    __shared__ int lh[VL];
    int b = blockIdx.x / CH, c0 = (blockIdx.x % CH)*256;
    int t = threadIdx.x;
    if (t < V) lh[t] = 0;
    __syncthreads();
    int i = c0 + t;
    if (i < S) atomicAdd(&lh[tok[b*S + i]], 1);
    __syncthreads();
    if (t < V && lh[t] > 0) atomicAdd(&tcnt[b*V + t], lh[t]);
}

__global__ void k_tok_off(const int* __restrict__ tcnt, int* toff, int V){
    int b = blockIdx.x;
    if (threadIdx.x != 0) return;
    int run = 0;
    for (int v = 0; v < V; ++v){ toff[b*V + v] = run; run += tcnt[b*V + v]; }
}

__global__ void k_tok_scatter(const int* __restrict__ tok, const int* __restrict__ toff,
                              int* tcur, int* __restrict__ bucket, int S, int V){
    __shared__ int lh[VL], lbase[VL], lcur[VL];
    int b = blockIdx.x / CH, c0 = (blockIdx.x % CH)*256;
    int t = threadIdx.x;
    if (t < V){ lh[t] = 0; lcur[t] = 0; }
    __syncthreads();
    int i = c0 + t;
    int v = -1;
    if (i < S){ v = tok[b*S + i]; atomicAdd(&lh[v], 1); }
    __syncthreads();
    if (t < V && lh[t] > 0) lbase[t] = atomicAdd(&tcur[b*V + t], lh[t]);
    __syncthreads();
    if (i < S){
        int p = lbase[v] + atomicAdd(&lcur[v], 1);
        bucket[b*S + toff[b*V + v] + p] = i;
    }
}

// Wr[c*256 + o*8 + k] = bf16(W[(o*S + c)*8 + k])
__global__ void k_transposeW(const float* __restrict__ W, bf16* __restrict__ Wr, int S){
    int c = blockIdx.x, t = threadIdx.x;
    Wr[c*256 + t] = __float2bfloat16(W[((t >> 3)*S + c)*8 + (t & 7)]);
}

// A[b*256V + (o*8+k)*V + v] = sum_{c in bucket(b,v)} Wr[c*256 + o*8+k]
__global__ void k_buildA(const bf16* __restrict__ Wr, const int* __restrict__ bucket,
                         const int* __restrict__ toff, const int* __restrict__ tcnt,
                         float* __restrict__ A, int S, int V){
    int bv = blockIdx.x;
    int b = bv / V, v = bv - b*V;
    int t = threadIdx.x;            // t = o*8+k
    const int* bk = bucket + b*S + toff[b*V + v];
    int m = tcnt[b*V + v];
    float acc = 0.f;
    int idx = 0;
    for (; idx + 4 <= m; idx += 4){
        int c0 = bk[idx], c1 = bk[idx+1], c2 = bk[idx+2], c3 = bk[idx+3];
        acc += b2f(Wr[c0*256 + t]);
        acc += b2f(Wr[c1*256 + t]);
        acc += b2f(Wr[c2*256 + t]);
        acc += b2f(Wr[c3*256 + t]);
    }
    for (; idx < m; ++idx) acc += b2f(Wr[bk[idx]*256 + t]);
    A[b*(256*V) + t*V + v] = acc;
}

// G[(o*M + m)*128 + j] = sum_l emb[v,l+k] * fcxrW[(o*121+l)*128 + j],  m=k*V+v
__global__ void k_buildG(const float* __restrict__ emb, const float* __restrict__ W,
                         bf16* __restrict__ G, int V, int MT4){
    __shared__ float rows[4][128];
    int o = blockIdx.x / MT4, mt = blockIdx.x % MT4;
    int t = threadIdx.x;   // 128, j
    int kk[4];
    #pragma unroll
    for (int mm = 0; mm < 4; ++mm){
        int m = mt*4 + mm;
        int k = m / V, v = m - k*V;
        kk[mm] = k;
        rows[mm][t] = emb[v*128 + t];
    }
    __syncthreads();
    float a0 = 0.f, a1 = 0.f, a2 = 0.f, a3 = 0.f;
    const float* Wo = W + o*121*128 + t;
    for (int l = 0; l < 121; ++l){
        float w = Wo[l*128];
        a0 += rows[0][l + kk[0]] * w;
        a1 += rows[1][l + kk[1]] * w;
        a2 += rows[2][l + kk[2]] * w;
        a3 += rows[3][l + kk[3]] * w;
    }
    int M = 8*V;
    int base = (o*M + mt*4)*128 + t;
    G[base      ] = __float2bfloat16(a0);
    G[base + 128] = __float2bfloat16(a1);
    G[base + 256] = __float2bfloat16(a2);
    G[base + 384] = __float2bfloat16(a3);
}

__global__ void k_bias0_init(const float* __restrict__ fcxrb, float* __restrict__ bias0){
    bias0[threadIdx.x] = fcxrb[threadIdx.x];
}

__global__ void k_bias0_acc(const float* __restrict__ W, const float* __restrict__ cb1,
                            const float* __restrict__ cb2, float* __restrict__ bias0){
    int o = blockIdx.x, j = threadIdx.x;
    float s = 0.f;
    const float* Wo = W + o*121*128 + j;
    for (int l = 0; l < 121; ++l) s += Wo[l*128];
    unsafeAtomicAdd(&bias0[j], 0.5f * (cb1[o] + cb2[o]) * s);
}

__global__ void k_init_out0(const float* __restrict__ bias0, float* __restrict__ out0){
    out0[blockIdx.x*128 + threadIdx.x] = bias0[threadIdx.x];
}

// out0[b,j] += 0.5 * sum_k X[b,k]*G[k,j]   (split-K, 8 b-rows per block)
__global__ void k_gemmR(const float* __restrict__ X, const bf16* __restrict__ G,
                        float* __restrict__ out0, int K){
    __shared__ float xs[8][256];
    int b0 = blockIdx.x * 8;
    int k0 = blockIdx.y * 256;
    int t = threadIdx.x;   // 128, j
    #pragma unroll
    for (int r = 0; r < 8; ++r){
        xs[r][t]       = X[(b0+r)*K + k0 + t];
        xs[r][t + 128] = X[(b0+r)*K + k0 + t + 128];
    }
    __syncthreads();
    float a0=0,a1=0,a2=0,a3=0,a4=0,a5=0,a6=0,a7=0;
    const bf16* Gp = G + (size_t)k0*128 + t;
    for (int kk = 0; kk < 256; ++kk){
        float g = b2f(Gp[kk*128]);
        a0 += xs[0][kk]*g; a1 += xs[1][kk]*g;
        a2 += xs[2][kk]*g; a3 += xs[3][kk]*g;
        a4 += xs[4][kk]*g; a5 += xs[5][kk]*g;
        a6 += xs[6][kk]*g; a7 += xs[7][kk]*g;
    }
    unsafeAtomicAdd(&out0[(b0+0)*128 + t], 0.5f*a0);
    unsafeAtomicAdd(&out0[(b0+1)*128 + t], 0.5f*a1);
    unsafeAtomicAdd(&out0[(b0+2)*128 + t], 0.5f*a2);
    unsafeAtomicAdd(&out0[(b0+3)*128 + t], 0.5f*a3);
    unsafeAtomicAdd(&out0[(b0+4)*128 + t], 0.5f*a4);
    unsafeAtomicAdd(&out0[(b0+5)*128 + t], 0.5f*a5);
    unsafeAtomicAdd(&out0[(b0+6)*128 + t], 0.5f*a6);
    unsafeAtomicAdd(&out0[(b0+7)*128 + t], 0.5f*a7);
}

extern "C" void kernel_launch(void* const* d_in, const int* in_sizes, int n_in,
                              void* d_out, int out_size, void* d_ws, size_t ws_size,
                              hipStream_t stream)
{
    (void)in_sizes; (void)n_in; (void)out_size; (void)ws_size;

    const float* pro_x  = (const float*)d_in[0];
    const int*   eidx   = (const int*)  d_in[1];
    const float* ew     = (const float*)d_in[2];
    const int*   pbatch = (const int*)  d_in[3];
    const int*   rna_g  = (const int*)  d_in[4];
    const int*   rna_l  = (const int*)  d_in[5];
    const float* emb1   = (const float*)d_in[6];
    const float* emb2   = (const float*)d_in[7];
    const float* convW1 = (const float*)d_in[8];
    const float* convb1 = (const float*)d_in[9];
    const float* convW2 = (const float*)d_in[10];
    const float* convb2 = (const float*)d_in[11];
    const float* fcxrW  = (const float*)d_in[12];
    const float* fcxrb  = (const float*)d_in[13];
    const float* g1W = (const float*)d_in[14];
    const float* g1b = (const float*)d_in[15];
    const float* g2W = (const float*)d_in[16];
    const float* g2b = (const float*)d_in[17];
    const float* g3W = (const float*)d_in[18];
    const float* g3b = (const float*)d_in[19];
    const float* bn1g = (const float*)d_in[20];
    const float* bn1b = (const float*)d_in[21];
    const float* bn2g = (const float*)d_in[22];
    const float* bn2b = (const float*)d_in[23];
    const float* bn3g = (const float*)d_in[24];
    const float* bn3b = (const float*)d_in[25];
    const float* fcg1W = (const float*)d_in[26];
    const float* fcg1b = (const float*)d_in[27];
    const float* fcg2W = (const float*)d_in[28];
    const float* fcg2b = (const float*)d_in[29];

    const int* e_src = eidx;
    const int* e_dst = eidx + NE;

    char* base = (char*)d_ws;
    size_t off = 0;
    auto alloc = [&](size_t bytes)->char*{
        off = (off + 255) & ~(size_t)255;
        char* p = base + off; off += bytes; return p;
    };

    // ---- zero zone (single memset) ----
    double* packed  = (double*)alloc(NN*8);
    int*   tcnt_g  = (int*)  alloc(NB*VG*4);
    int*   tcur_g  = (int*)  alloc(NB*VG*4);
    int*   tcnt_l  = (int*)  alloc(NB*VL*4);
    int*   tcur_l  = (int*)  alloc(NB*VL*4);
    float* bnsum1  = (float*)alloc(2*33*4);
    float* bnsum2  = (float*)alloc(2*66*4);
    float* bnsum3  = (float*)alloc(2*132*4);
    float* poolsum = (float*)alloc(NG*132*4);
    size_t zero_bytes = (off + 255) & ~(size_t)255;

    // ---- persistent buffers ----
    int*    cnt    = (int*)   alloc(NN*4);
    float2* dis12  = (float2*)alloc(NN*8);
    float2* self12 = (float2*)alloc(NN*8);
    int*    offs   = (int*)   alloc(NN*4);
    int*    bsum   = (int*)   alloc(64*4);
    float*  bnscale= (float*) alloc(132*4);
    float*  bnshift= (float*) alloc(132*4);
    float*  h      = (float*) alloc(NG*1024*4);
    int*    gstart = (int*)   alloc((NG+1)*4);
    float4* epk    = (float4*)alloc((size_t)NE*16);
    float*  bufA   = (float*) alloc((size_t)NN*68*4);    // agg output (max Fs=68)
    float*  bufB   = (float*) alloc((size_t)NN*132*4);   // gemm output (max OF=132)
    bf16*   xbA    = (bf16*)  alloc((size_t)NN*132*2);   // bf16 features
    bf16*   xbB    = (bf16*)  alloc((size_t)NN*132*2);

    // slot aliases xbA (slot consumed by k_edge_scatter before L1 bn_apply
    // writes xbA). xb0 aliases xbB (consumed by L1 agg before L2 bn_apply).
    int*  slot = (int*)xbA;
    bf16* xb0  = (bf16*)xbB;

    float* out0 = (float*)d_out;          // xc_rna
    float* out1 = (float*)d_out + 16384;  // xp_out

    // ---- RNA-phase scratch aliased onto bufB (RNA completes before
    // L1 gemm writes bufB; same stream serializes) ----
    {
        char* rb = (char*)bufB;
        size_t ro = 0;
        auto ralloc = [&](size_t bytes)->char*{
            ro = (ro + 255) & ~(size_t)255;
            char* p = rb + ro; ro += bytes; return p;
        };
        int* toff_g   = (int*)ralloc(NB*VG*4);
        int* toff_l   = (int*)ralloc(NB*VL*4);
        int* bucket_g = (int*)ralloc((size_t)NB*SG*4);
        int* bucket_l = (int*)ralloc((size_t)NB*SL*4);
        bf16* Wr1     = (bf16*)ralloc((size_t)SG*256*2);
        bf16* Wr2     = (bf16*)ralloc((size_t)SL*256*2);
        float* Ag     = (float*)ralloc((size_t)NB*256*VG*4);
        float* Al     = (float*)ralloc((size_t)NB*256*VL*4);
        bf16* G1      = (bf16*)ralloc((size_t)32*8*VG*128*2);
        bf16* G2      = (bf16*)ralloc((size_t)32*8*VL*128*2);
        float* bias0  = (float*)ralloc(128*4);

        hipMemsetAsync(d_ws, 0, zero_bytes, stream);

        // token bucketing
        k_tok_count<<<NB*CH, 256, 0, stream>>>(rna_g, tcnt_g, SG, VG);
        k_tok_count<<<NB*CH, 256, 0, stream>>>(rna_l, tcnt_l, SL, VL);
        k_tok_off<<<NB, 64, 0, stream>>>(tcnt_g, toff_g, VG);
        k_tok_off<<<NB, 64, 0, stream>>>(tcnt_l, toff_l, VL);
        k_tok_scatter<<<NB*CH, 256, 0, stream>>>(rna_g, toff_g, tcur_g, bucket_g, SG, VG);
        k_tok_scatter<<<NB*CH, 256, 0, stream>>>(rna_l, toff_l, tcur_l, bucket_l, SL, VL);
        // conv weight transpose + bucketed A
        k_transposeW<<<SG, 256, 0, stream>>>(convW1, Wr1, SG);
        k_transposeW<<<SL, 256, 0, stream>>>(convW2, Wr2, SL);
        k_buildA<<<NB*VG, 256, 0, stream>>>(Wr1, bucket_g, toff_g, tcnt_g, Ag, SG, VG);
        k_buildA<<<NB*VL, 256, 0, stream>>>(Wr2, bucket_l, toff_l, tcnt_l, Al, SL, VL);
        // fold emb into fcxr weight
        k_buildG<<<32*(8*VG/4), 128, 0, stream>>>(emb1, fcxrW, G1, VG, 8*VG/4);
        k_buildG<<<32*(8*VL/4), 128, 0, stream>>>(emb2, fcxrW, G2, VL, 8*VL/4);
        k_bias0_init<<<1, 128, 0, stream>>>(fcxrb, bias0);
        k_bias0_acc<<<32, 128, 0, stream>>>(fcxrW, convb1, convb2, bias0);
        k_init_out0<<<NB, 128, 0, stream>>>(bias0, out0);
        // out0 = bias0 + 0.5*(Ag·G1 + Al·G2)
        k_gemmR<<<dim3(16, (8*VG*32)/256), 128, 0, stream>>>(Ag, G1, out0, 8*VG*32);
        k_gemmR<<<dim3(16, (8*VL*32)/256), 128, 0, stream>>>(Al, G2, out0, 8*VL*32);
    }

    // ---------------- graph prep ----------------
    k_edge_deg<<<(NE+255)/256, 256, 0, stream>>>(e_dst, ew, packed, slot);
    k_node_dis<<<(NN+255)/256, 256, 0, stream>>>(packed, cnt, dis12, self12);
    k_scan1<<<49, 256, 0, stream>>>(cnt, bsum);
    k_scan2<<<1, 64, 0, stream>>>(bsum, 49);
    k_scan3<<<49, 256, 0, stream>>>(cnt, bsum, offs);
    k_edge_scatter<<<(NE+255)/256, 256, 0, stream>>>(e_src, e_dst, ew, dis12,
                                                     offs, slot, epk);
    k_cast<<<(NN*36+255)/256, 256, 0, stream>>>(pro_x, xb0);

    // ---------------- GCN layer 1 (33 -> 33), padded stride 36 ----------------
    k_aggT<9,4><<<NN/4, 256, 0, stream>>>(xb0, epk, offs, cnt, self12, 0, bufA);
    k_gemm_node8<<<NN/8, 64, 8*36*4, stream>>>(bufA, g1W, g1b, bufB, 33, 36, 33);
    k_bn_stats<<<256, 64, 0, stream>>>(bufB, bnsum1, 33);
    k_bn_finalize<<<1, 192, 0, stream>>>(bnsum1, bn1g, bn1b, bnscale, bnshift, 33);
    k_bn_apply<<<NN, 64, 0, stream>>>(bufB, bnscale, bnshift, xbA, 33, 36);

    // ---------------- GCN layer 2 (33 -> 66) ----------------
    k_aggT<9,4><<<NN/4, 256, 0, stream>>>(xbA, epk, offs, cnt, self12, 1, bufA);
    k_gemm_node8<<<NN/8, 128, 8*36*4, stream>>>(bufA, g2W, g2b, bufB, 33, 36, 66);
    k_bn_stats<<<256, 128, 0, stream>>>(bufB, bnsum2, 66);
    k_bn_finalize<<<1, 192, 0, stream>>>(bnsum2, bn2g, bn2b, bnscale, bnshift, 66);
    k_bn_apply<<<NN, 128, 0, stream>>>(bufB, bnscale, bnshift, xbB, 66, 68);

    // ---------------- GCN layer 3 (66 -> 132), padded stride 68 ----------------
    k_aggT<17,2><<<NN/4, 256, 0, stream>>>(xbB, epk, offs, cnt, self12, 1, bufA);
    k_gemm_node8<<<NN/8, 192, 8*68*4, stream>>>(bufA, g3W, g3b, bufB, 66, 68, 132);
    k_bn_stats<<<256, 192, 0, stream>>>(bufB, bnsum3, 132);
    k_bn_finalize<<<1, 192, 0, stream>>>(bnsum3, bn3g, bn3b, bnscale, bnshift, 132);
    k_bn_apply<<<NN, 192, 0, stream>>>(bufB, bnscale, bnshift, xbA, 132, 132);

    // ---------------- pool + head ----------------
    k_gbounds<<<(NN+255)/256, 256, 0, stream>>>(pbatch, gstart);
    k_poolsum<<<dim3(NG,4), 192, 0, stream>>>(xbA, gstart, poolsum);
    k_fcg1<<<NG, 1024, 0, stream>>>(poolsum, gstart, fcg1W, fcg1b, h);
    k_fcg2<<<NG, 1024, 0, stream>>>(h, fcg2W, fcg2b, out1);
}